// Round 1
// 571.298 us; speedup vs baseline: 7.6793x; 7.6793x over previous
//
#include <hip/hip_runtime.h>
#include <hip/hip_bf16.h>

typedef __hip_bfloat16 bf16;
typedef __attribute__((ext_vector_type(8))) short bf16x8;
typedef __attribute__((ext_vector_type(4))) float f32x4;

#define E_DIM 1024
#define H_DIM 16
#define N_DIM 4096
#define B_DIM 4
#define D_DIM 64
#define G_WIN 32   // N / 128
#define NC 32      // N / 128
#define M_ROWS 16384  // N*B

// ---------------- fp32 -> bf16 bulk convert (8 elems/thread) ----------------
__global__ __launch_bounds__(256) void cvt_f32_bf16(
    const float* __restrict__ in, bf16* __restrict__ out)
{
    int i = (blockIdx.x * 256 + threadIdx.x) * 8;
    float4 f0 = *(const float4*)(in + i);
    float4 f1 = *(const float4*)(in + i + 4);
    union { bf16 t[8]; uint4 u; } pk;
    pk.t[0] = (bf16)f0.x; pk.t[1] = (bf16)f0.y; pk.t[2] = (bf16)f0.z; pk.t[3] = (bf16)f0.w;
    pk.t[4] = (bf16)f1.x; pk.t[5] = (bf16)f1.y; pk.t[6] = (bf16)f1.z; pk.t[7] = (bf16)f1.w;
    *(uint4*)(out + i) = pk.u;
}

// ---------------- MFMA GEMM ----------------
// out[m,e] = sum_k A[m,k] * W[e,k]  (A bf16 row-major [M][K], W fp32 row-major [e][k])
// 128x128 tile, 4 waves of 64x64, mfma_f32_16x16x32_bf16, BK=32.
// MODE 0: (val + bias)*scale -> bf16 scatter [B,H,N,D]   (m=n*B+b, e=h*64+d)
// MODE 1: val + bias -> fp32 row-major [M][E]
template<int MODE>
__global__ __launch_bounds__(256) void gemm_mfma(
    const bf16* __restrict__ A, const float* __restrict__ W,
    const float* __restrict__ bias, float scale,
    bf16* __restrict__ out_bf, float* __restrict__ out_f)
{
    __shared__ bf16 As[128 * 32];
    __shared__ bf16 Bs[128 * 32];
    int tid  = threadIdx.x;
    int lane = tid & 63;
    int wv   = tid >> 6;
    int wm   = (wv >> 1) * 64;
    int wn   = (wv & 1) * 64;
    int quad = lane >> 4;
    int l16  = lane & 15;
    int row0 = blockIdx.y * 128;
    int col0 = blockIdx.x * 128;
    f32x4 acc[4][4] = {};

    for (int k0 = 0; k0 < E_DIM; k0 += 32) {
        // A tile: 128 rows x 32 cols bf16 via global_load_lds (16B per lane)
#pragma unroll
        for (int i = 0; i < 2; i++) {
            int idx = tid + i * 256;
            int r = idx >> 2, c = idx & 3;
            const bf16* g = A + (size_t)(row0 + r) * E_DIM + k0 + c * 8;
            __builtin_amdgcn_global_load_lds(
                (const __attribute__((address_space(1))) void*)g,
                (__attribute__((address_space(3))) void*)(As + idx * 8), 16, 0, 0);
        }
        // W tile: fp32 -> bf16 on the fly
#pragma unroll
        for (int i = 0; i < 2; i++) {
            int idx = tid + i * 256;
            int e = idx >> 2, c = idx & 3;
            const float* wr = W + (size_t)(col0 + e) * E_DIM + k0 + c * 8;
            float4 f0 = *(const float4*)wr;
            float4 f1 = *(const float4*)(wr + 4);
            union { bf16 t[8]; uint4 u; } pk;
            pk.t[0] = (bf16)f0.x; pk.t[1] = (bf16)f0.y;
            pk.t[2] = (bf16)f0.z; pk.t[3] = (bf16)f0.w;
            pk.t[4] = (bf16)f1.x; pk.t[5] = (bf16)f1.y;
            pk.t[6] = (bf16)f1.z; pk.t[7] = (bf16)f1.w;
            *(uint4*)(Bs + idx * 8) = pk.u;
        }
        __syncthreads();

        bf16x8 af[4], bfr[4];
#pragma unroll
        for (int t = 0; t < 4; t++) {
            af[t]  = *(const bf16x8*)(As + (wm + t * 16 + l16) * 32 + quad * 8);
            bfr[t] = *(const bf16x8*)(Bs + (wn + t * 16 + l16) * 32 + quad * 8);
        }
#pragma unroll
        for (int mt = 0; mt < 4; mt++)
#pragma unroll
            for (int nt = 0; nt < 4; nt++)
                acc[mt][nt] = __builtin_amdgcn_mfma_f32_16x16x32_bf16(
                    af[mt], bfr[nt], acc[mt][nt], 0, 0, 0);
        __syncthreads();
    }

#pragma unroll
    for (int mt = 0; mt < 4; mt++)
#pragma unroll
        for (int nt = 0; nt < 4; nt++)
#pragma unroll
            for (int rg = 0; rg < 4; rg++) {
                int m = row0 + wm + mt * 16 + quad * 4 + rg;
                int e = col0 + wn + nt * 16 + l16;
                float val = acc[mt][nt][rg];
                if (MODE == 0) {
                    float v2 = (val + bias[e]) * scale;
                    int n = m >> 2, bb = m & 3;
                    int h = e >> 6, d = e & 63;
                    out_bf[((((size_t)bb * H_DIM + h) * N_DIM + n) * D_DIM) + d] = (bf16)v2;
                } else {
                    out_f[(size_t)m * E_DIM + e] = val + bias[e];
                }
            }
}

// ---------------- Chunk stats: rf_k_bar, rfa_chunk per (b,h,c) ----------------
__global__ __launch_bounds__(128) void chunk_stats(
    const bf16* __restrict__ q_s, const bf16* __restrict__ kbuf, const bf16* __restrict__ vbuf,
    const float* __restrict__ mqw, const float* __restrict__ mqb,
    const float* __restrict__ mqg, const float* __restrict__ mqbe,
    const float* __restrict__ mkw, const float* __restrict__ mkb,
    const float* __restrict__ mkg, const float* __restrict__ mkbe,
    float* __restrict__ rf_k_bar, float* __restrict__ rfa_chunk)
{
    int bid = blockIdx.x;
    int c = bid % NC;
    int bh = bid / NC;           // b*H + h
    int tid = threadIdx.x;

    __shared__ float qm[64], km[64], qb_s[64], kb_s[64], mu_s[64], sc[128];
    __shared__ float stats[4];

    size_t base = ((size_t)bh * N_DIM + c * 128) * D_DIM;

    if (tid < 64) {
        float s = 0.f;
        for (int p = 0; p < 128; p++) s += (float)q_s[base + p * 64 + tid];
        qm[tid] = s * (1.0f / 128.0f);
    } else {
        int d = tid - 64;
        float s = 0.f;
        for (int p = 0; p < 128; p++) s += (float)kbuf[base + p * 64 + d];
        km[d] = s * (1.0f / 128.0f);
    }
    __syncthreads();

    if (tid < 64) {
        float t = mqb[tid];
        for (int d2 = 0; d2 < 64; d2++) t += qm[d2] * mqw[tid * 64 + d2];
        qb_s[tid] = t;
    } else {
        int d = tid - 64;
        float t = mkb[d];
        for (int d2 = 0; d2 < 64; d2++) t += km[d2] * mkw[d * 64 + d2];
        kb_s[d] = t;
    }
    __syncthreads();

    if (tid == 0) {
        float m = 0.f;
        for (int d = 0; d < 64; d++) m += qb_s[d];
        m *= (1.0f / 64.0f);
        float vv = 0.f;
        for (int d = 0; d < 64; d++) { float x = qb_s[d] - m; vv += x * x; }
        vv *= (1.0f / 64.0f);
        stats[0] = m; stats[1] = rsqrtf(vv + 1e-5f);
    } else if (tid == 64) {
        float m = 0.f;
        for (int d = 0; d < 64; d++) m += kb_s[d];
        m *= (1.0f / 64.0f);
        float vv = 0.f;
        for (int d = 0; d < 64; d++) { float x = kb_s[d] - m; vv += x * x; }
        vv *= (1.0f / 64.0f);
        stats[2] = m; stats[3] = rsqrtf(vv + 1e-5f);
    }
    __syncthreads();

    if (tid < 64) {
        float qn = (qb_s[tid] - stats[0]) * stats[1] * mqg[tid] + mqbe[tid];
        float kn = (kb_s[tid] - stats[2]) * stats[3] * mkg[tid] + mkbe[tid];
        mu_s[tid] = qn + kn;
        rf_k_bar[(size_t)bh * NC * 64 + c * 64 + tid] = kn;
    }
    __syncthreads();

    {
        float dot = 0.f, ss = 0.f;
        const bf16* kr = kbuf + base + tid * 64;
        for (int d = 0; d < 64; d++) {
            float kv = (float)kr[d];
            dot += mu_s[d] * kv;
            ss += kv * kv;
        }
        sc[tid] = dot * 0.125f - 0.125f * 0.5f * ss;
    }
    __syncthreads();
    if (tid == 0) {
        float m = sc[0];
        for (int p = 1; p < 128; p++) m = fmaxf(m, sc[p]);
        stats[0] = m;
    }
    __syncthreads();
    float e = expf(sc[tid] - stats[0]);
    sc[tid] = e;
    __syncthreads();
    if (tid == 0) {
        float s = 0.f;
        for (int p = 0; p < 128; p++) s += sc[p];
        stats[1] = 1.0f / s;
    }
    __syncthreads();
    sc[tid] *= stats[1];
    __syncthreads();

    if (tid < 64) {
        float acc = 0.f;
        for (int p = 0; p < 128; p++) acc += sc[p] * (float)vbuf[base + p * 64 + tid];
        rfa_chunk[(size_t)bh * NC * 64 + c * 64 + tid] = acc;
    }
}

// ---------------- Windowed attention per (b,h,g) — MFMA version --------------
// 512 threads = 8 waves; wave wv owns query rows [g*128 + wv*16, +16).
// LDS: Ks[288][72] bf16 (256 local K rows + 32 rf_k_bar rows, pad 72 kills
//      power-of-2 bank stride); Vt[64][296] = V^T (d-major) with rfa_chunk^T
//      appended as key-cols 256..287; Pw[8][16][40] per-wave P transpose
//      scratch (acc C-layout -> A-fragment layout).
// S kept in registers: acc[18] f32x4 per lane (18 col-tiles of 16).
// Softmax row-reduce = 4x shfl_xor within the 16-lane column group.
// Normalization folded into the epilogue (scale outputs by 1/sum).
__global__ __launch_bounds__(512, 2) void attn_kernel(
    const bf16* __restrict__ qin, const bf16* __restrict__ kbuf, const bf16* __restrict__ vbuf,
    const float* __restrict__ rf_k_bar, const float* __restrict__ rfa_chunk,
    bf16* __restrict__ aout)
{
    int bid = blockIdx.x;
    int g = bid & (G_WIN - 1);
    int bh = bid / G_WIN;          // b*H + h
    int b = bh >> 4, h = bh & 15;
    int tid = threadIdx.x;
    int lane = tid & 63;
    int wv = tid >> 6;             // 0..7
    int q4 = lane >> 4;            // 0..3
    int l16 = lane & 15;

    __shared__ __align__(16) short Ks[288 * 72];   // 41,472 B
    __shared__ __align__(16) short Vt[64 * 296];   // 37,888 B
    __shared__ __align__(16) short Pw[8 * 16 * 40]; // 10,240 B

    size_t kvbase = (size_t)bh * N_DIM * D_DIM;
    int k0g = g * 128 - 128;       // global key index of local j=0

    // ---- stage K local: 256 keys x 64 d (16B chunks, padded rows) ----
#pragma unroll
    for (int i = 0; i < 4; i++) {
        int ci = tid + i * 512;            // 0..2047
        int key = ci >> 3, chc = ci & 7;
        int kidx = k0g + key; if (kidx < 0) kidx = 0;   // masked later
        bf16x8 v = *(const bf16x8*)(kbuf + kvbase + (size_t)kidx * 64 + chc * 8);
        *(bf16x8*)(Ks + key * 72 + chc * 8) = v;
    }
    // ---- stage rf_k_bar (fp32 32x64) -> Ks rows 256..287 ----
    if (tid < 256) {
        int c = tid >> 3, chc = tid & 7;
        const float* src = rf_k_bar + (size_t)bh * NC * 64 + c * 64 + chc * 8;
        float4 f0 = *(const float4*)src;
        float4 f1 = *(const float4*)(src + 4);
        union { bf16 t[8]; bf16x8 v; } pk;
        pk.t[0] = (bf16)f0.x; pk.t[1] = (bf16)f0.y;
        pk.t[2] = (bf16)f0.z; pk.t[3] = (bf16)f0.w;
        pk.t[4] = (bf16)f1.x; pk.t[5] = (bf16)f1.y;
        pk.t[6] = (bf16)f1.z; pk.t[7] = (bf16)f1.w;
        *(bf16x8*)(Ks + (256 + c) * 72 + chc * 8) = pk.v;
    }
    // ---- stage V transposed: Vt[d][key], key varies fastest across lanes ----
#pragma unroll
    for (int i = 0; i < 4; i++) {
        int ci = tid + i * 512;            // 0..2047
        int key = ci & 255, dc = ci >> 8;  // dc 0..7
        int kidx = k0g + key; if (kidx < 0) kidx = 0;
        union { bf16x8 v; short s[8]; } u;
        u.v = *(const bf16x8*)(vbuf + kvbase + (size_t)kidx * 64 + dc * 8);
#pragma unroll
        for (int jj = 0; jj < 8; jj++)
            Vt[(dc * 8 + jj) * 296 + key] = u.s[jj];
    }
    // ---- stage rfa_chunk^T -> Vt key-cols 256..287 ----
    if (tid < 256) {
        int d = tid >> 2, cg = tid & 3;
        const float* rc = rfa_chunk + (size_t)bh * NC * 64;
#pragma unroll
        for (int jj = 0; jj < 8; jj++) {
            int c = cg * 8 + jj;
            union { bf16 bv; short s; } cv;
            cv.bv = (bf16)rc[(size_t)c * 64 + d];
            Vt[d * 296 + 256 + c] = cv.s;
        }
    }

    // ---- Q fragments (global, rows are wave-private) ----
    bf16x8 aq[2];
    {
        const bf16* qrow = qin + kvbase + (size_t)(g * 128 + wv * 16 + l16) * 64 + q4 * 8;
        aq[0] = *(const bf16x8*)qrow;
        aq[1] = *(const bf16x8*)(qrow + 32);
    }

    __syncthreads();

    // ---- QK^T: S[16 x 288] per wave, in registers ----
    f32x4 acc[18] = {};
#pragma unroll
    for (int ct = 0; ct < 18; ct++) {
#pragma unroll
        for (int kc = 0; kc < 2; kc++) {
            bf16x8 bk = *(const bf16x8*)(Ks + (ct * 16 + l16) * 72 + kc * 32 + q4 * 8);
            acc[ct] = __builtin_amdgcn_mfma_f32_16x16x32_bf16(aq[kc], bk, acc[ct], 0, 0, 0);
        }
    }

    // ---- mask + row max ----
    float mrow[4] = { -1e30f, -1e30f, -1e30f, -1e30f };
#pragma unroll
    for (int ct = 0; ct < 18; ct++) {
        int j = ct * 16 + l16;
        bool jval = (j < 256) ? (k0g + j >= 0) : ((j - 256) < g);
#pragma unroll
        for (int rg = 0; rg < 4; rg++) {
            int i = wv * 16 + q4 * 4 + rg;              // row within window
            bool ok = jval && (j >= 256 || j <= i + 128);
            float s = ok ? acc[ct][rg] : -1e9f;
            acc[ct][rg] = s;
            mrow[rg] = fmaxf(mrow[rg], s);
        }
    }
#pragma unroll
    for (int rg = 0; rg < 4; rg++) {
        float v = mrow[rg];
        v = fmaxf(v, __shfl_xor(v, 1));
        v = fmaxf(v, __shfl_xor(v, 2));
        v = fmaxf(v, __shfl_xor(v, 4));
        v = fmaxf(v, __shfl_xor(v, 8));
        mrow[rg] = v;
    }

    // ---- exp + row sum (normalization deferred to epilogue) ----
    float rsum[4] = { 0.f, 0.f, 0.f, 0.f };
#pragma unroll
    for (int ct = 0; ct < 18; ct++)
#pragma unroll
        for (int rg = 0; rg < 4; rg++) {
            float p = __expf(acc[ct][rg] - mrow[rg]);
            acc[ct][rg] = p;
            rsum[rg] += p;
        }
    float rinv[4];
#pragma unroll
    for (int rg = 0; rg < 4; rg++) {
        float v = rsum[rg];
        v += __shfl_xor(v, 1);
        v += __shfl_xor(v, 2);
        v += __shfl_xor(v, 4);
        v += __shfl_xor(v, 8);
        rinv[rg] = 1.0f / v;
    }

    // ---- P·V: transpose P through wave-private LDS scratch, MFMA ----
    f32x4 accO[4] = {};
    short* pw = Pw + wv * (16 * 40);
#pragma unroll
    for (int cc = 0; cc < 9; cc++) {
#pragma unroll
        for (int half = 0; half < 2; half++) {
            int ct = cc * 2 + half;
#pragma unroll
            for (int rg = 0; rg < 4; rg++) {
                union { bf16 bv; short s; } cv;
                cv.bv = (bf16)acc[ct][rg];
                pw[(q4 * 4 + rg) * 40 + half * 16 + l16] = cv.s;
            }
        }
        bf16x8 ap = *(const bf16x8*)(pw + l16 * 40 + q4 * 8);
#pragma unroll
        for (int dt = 0; dt < 4; dt++) {
            bf16x8 bv = *(const bf16x8*)(Vt + (dt * 16 + l16) * 296 + cc * 32 + q4 * 8);
            accO[dt] = __builtin_amdgcn_mfma_f32_16x16x32_bf16(ap, bv, accO[dt], 0, 0, 0);
        }
    }

    // ---- epilogue: normalize, store row-major [n*B + b][h*64 + d] ----
    int nbase = g * 128 + wv * 16 + q4 * 4;
#pragma unroll
    for (int dt = 0; dt < 4; dt++)
#pragma unroll
        for (int rg = 0; rg < 4; rg++) {
            float o = accO[dt][rg] * rinv[rg];
            int nn = nbase + rg;
            int d = dt * 16 + l16;
            aout[((size_t)nn * B_DIM + b) * E_DIM + h * 64 + d] = (bf16)o;
        }
}

extern "C" void kernel_launch(void* const* d_in, const int* in_sizes, int n_in,
                              void* d_out, int out_size, void* d_ws, size_t ws_size,
                              hipStream_t stream) {
    const float* query = (const float*)d_in[0];
    const float* Wq   = (const float*)d_in[1];
    const float* bq   = (const float*)d_in[2];
    const float* Wk   = (const float*)d_in[3];
    const float* bk   = (const float*)d_in[4];
    const float* Wv   = (const float*)d_in[5];
    const float* bv   = (const float*)d_in[6];
    const float* Wo   = (const float*)d_in[7];
    const float* bo   = (const float*)d_in[8];
    const float* mqw  = (const float*)d_in[9];
    const float* mqb  = (const float*)d_in[10];
    const float* mqg  = (const float*)d_in[11];
    const float* mqbe = (const float*)d_in[12];
    const float* mkw  = (const float*)d_in[13];
    const float* mkb  = (const float*)d_in[14];
    const float* mkg  = (const float*)d_in[15];
    const float* mkbe = (const float*)d_in[16];

    const size_t SZ = (size_t)B_DIM * H_DIM * N_DIM * D_DIM; // 16,777,216 elems
    const size_t STATS = (size_t)B_DIM * H_DIM * NC * D_DIM; // 131,072 elems

    // ws (65 MiB proven): k,v bf16 + fp32 stats
    bf16* kb = (bf16*)d_ws;
    bf16* vb = kb + SZ;
    float* rf_k_bar  = (float*)(vb + SZ);
    float* rfa_chunk = rf_k_bar + STATS;

    // d_out (64 MiB fp32): half1 = q bf16 [B,H,N,D]; half2 = query_bf16, later attn-out bf16.
    float* outf = (float*)d_out;
    bf16* qb  = (bf16*)d_out;      // 32 MiB
    bf16* qbf = qb + SZ;           // 32 MiB: query in bf16, then attn output

    dim3 gblk(256);
    dim3 ggrd(E_DIM / 128, M_ROWS / 128);   // (8, 128)

    // 1. query fp32 -> bf16
    cvt_f32_bf16<<<(M_ROWS * E_DIM) / (256 * 8), 256, 0, stream>>>(query, qbf);

    // 2. projections (MFMA)
    gemm_mfma<0><<<ggrd, gblk, 0, stream>>>(qbf, Wq, bq, 0.125f, qb, nullptr);
    gemm_mfma<0><<<ggrd, gblk, 0, stream>>>(qbf, Wk, bk, 1.0f, kb, nullptr);
    gemm_mfma<0><<<ggrd, gblk, 0, stream>>>(qbf, Wv, bv, 1.0f, vb, nullptr);

    // 3. chunk stats
    chunk_stats<<<B_DIM * H_DIM * NC, 128, 0, stream>>>(
        qb, kb, vb, mqw, mqb, mqg, mqbe, mkw, mkb, mkg, mkbe, rf_k_bar, rfa_chunk);

    // 4. attention (MFMA) -> qbf region (query_bf dead), row-major [N*B][E] bf16
    attn_kernel<<<B_DIM * H_DIM * G_WIN, 512, 0, stream>>>(
        qb, kb, vb, rf_k_bar, rfa_chunk, qbf);

    // 5. stage attn output into kb (dead) so final GEMM doesn't read d_out
    (void)hipMemcpyAsync(kb, qbf, SZ * sizeof(bf16), hipMemcpyDeviceToDevice, stream);

    // 6. output projection (MFMA), fp32 out over all of d_out
    gemm_mfma<1><<<ggrd, gblk, 0, stream>>>(kb, Wo, bo, 1.0f, nullptr, outf);
}

// Round 2
// 455.147 us; speedup vs baseline: 9.6390x; 1.2552x over previous
//
#include <hip/hip_runtime.h>
#include <hip/hip_bf16.h>

typedef __hip_bfloat16 bf16;
typedef __attribute__((ext_vector_type(8))) short bf16x8;
typedef __attribute__((ext_vector_type(4))) float f32x4;

#define E_DIM 1024
#define H_DIM 16
#define N_DIM 4096
#define B_DIM 4
#define D_DIM 64
#define G_WIN 32   // N / 128
#define NC 32      // N / 128
#define M_ROWS 16384  // N*B

// ---------------- fp32 -> bf16 bulk convert (8 elems/thread) ----------------
__global__ __launch_bounds__(256) void cvt_f32_bf16(
    const float* __restrict__ in, bf16* __restrict__ out)
{
    int i = (blockIdx.x * 256 + threadIdx.x) * 8;
    float4 f0 = *(const float4*)(in + i);
    float4 f1 = *(const float4*)(in + i + 4);
    union { bf16 t[8]; uint4 u; } pk;
    pk.t[0] = (bf16)f0.x; pk.t[1] = (bf16)f0.y; pk.t[2] = (bf16)f0.z; pk.t[3] = (bf16)f0.w;
    pk.t[4] = (bf16)f1.x; pk.t[5] = (bf16)f1.y; pk.t[6] = (bf16)f1.z; pk.t[7] = (bf16)f1.w;
    *(uint4*)(out + i) = pk.u;
}

// ---------------- MFMA GEMM ----------------
// out[m,e] = sum_k A[m,k] * W[e,k]  (A bf16 row-major [M][K])
// 128x128 tile, 4 waves of 64x64, mfma_f32_16x16x32_bf16, BK=32.
// 1-D grid with chunked XCD swizzle: logical = (bid&7)*(nwg/8) + (bid>>3),
// col-fastest tiles -> each XCD owns a contiguous row-band x all cols so its
// W panel set (2 MiB bf16) stays L2-resident and A panels are fetched once.
// WB16: W is pre-converted bf16 [e][k] (global_load_lds staging, no VALU).
// else: W is fp32 [e][k], converted to bf16 on the fly (fallback).
// MODE 0: (val + bias)*scale -> bf16 scatter [B,H,N,D]   (m=n*B+b, e=h*64+d)
// MODE 1: val + bias -> fp32 row-major [M][E]
template<int MODE, bool WB16>
__global__ __launch_bounds__(256) void gemm_mfma(
    const bf16* __restrict__ A, const void* __restrict__ Wp,
    const float* __restrict__ bias, float scale,
    bf16* __restrict__ out_bf, float* __restrict__ out_f)
{
    __shared__ bf16 As[128 * 32];
    __shared__ bf16 Bs[128 * 32];
    int tid  = threadIdx.x;
    int lane = tid & 63;
    int wv   = tid >> 6;
    int wm   = (wv >> 1) * 64;
    int wn   = (wv & 1) * 64;
    int quad = lane >> 4;
    int l16  = lane & 15;

    // XCD-chunked swizzle (nwg divisible by 8)
    int nwg = gridDim.x;
    int per = nwg >> 3;
    int logical = (blockIdx.x & 7) * per + (blockIdx.x >> 3);
    int col0 = (logical & 7) * 128;      // 8 col tiles (E=1024)
    int row0 = (logical >> 3) * 128;

    f32x4 acc[4][4] = {};

    for (int k0 = 0; k0 < E_DIM; k0 += 32) {
        // A tile: 128 rows x 32 cols bf16 via global_load_lds (16B per lane)
#pragma unroll
        for (int i = 0; i < 2; i++) {
            int idx = tid + i * 256;
            int r = idx >> 2, c = idx & 3;
            const bf16* g = A + (size_t)(row0 + r) * E_DIM + k0 + c * 8;
            __builtin_amdgcn_global_load_lds(
                (const __attribute__((address_space(1))) void*)g,
                (__attribute__((address_space(3))) void*)(As + idx * 8), 16, 0, 0);
        }
        if constexpr (WB16) {
            // W tile: bf16 via global_load_lds, same pattern as A
            const bf16* Wb = (const bf16*)Wp;
#pragma unroll
            for (int i = 0; i < 2; i++) {
                int idx = tid + i * 256;
                int e = idx >> 2, c = idx & 3;
                const bf16* g = Wb + (size_t)(col0 + e) * E_DIM + k0 + c * 8;
                __builtin_amdgcn_global_load_lds(
                    (const __attribute__((address_space(1))) void*)g,
                    (__attribute__((address_space(3))) void*)(Bs + idx * 8), 16, 0, 0);
            }
        } else {
            // W tile: fp32 -> bf16 on the fly (fallback when ws too small)
            const float* Wf = (const float*)Wp;
#pragma unroll
            for (int i = 0; i < 2; i++) {
                int idx = tid + i * 256;
                int e = idx >> 2, c = idx & 3;
                const float* wr = Wf + (size_t)(col0 + e) * E_DIM + k0 + c * 8;
                float4 f0 = *(const float4*)wr;
                float4 f1 = *(const float4*)(wr + 4);
                union { bf16 t[8]; uint4 u; } pk;
                pk.t[0] = (bf16)f0.x; pk.t[1] = (bf16)f0.y;
                pk.t[2] = (bf16)f0.z; pk.t[3] = (bf16)f0.w;
                pk.t[4] = (bf16)f1.x; pk.t[5] = (bf16)f1.y;
                pk.t[6] = (bf16)f1.z; pk.t[7] = (bf16)f1.w;
                *(uint4*)(Bs + idx * 8) = pk.u;
            }
        }
        __syncthreads();

        bf16x8 af[4], bfr[4];
#pragma unroll
        for (int t = 0; t < 4; t++) {
            af[t]  = *(const bf16x8*)(As + (wm + t * 16 + l16) * 32 + quad * 8);
            bfr[t] = *(const bf16x8*)(Bs + (wn + t * 16 + l16) * 32 + quad * 8);
        }
#pragma unroll
        for (int mt = 0; mt < 4; mt++)
#pragma unroll
            for (int nt = 0; nt < 4; nt++)
                acc[mt][nt] = __builtin_amdgcn_mfma_f32_16x16x32_bf16(
                    af[mt], bfr[nt], acc[mt][nt], 0, 0, 0);
        __syncthreads();
    }

#pragma unroll
    for (int mt = 0; mt < 4; mt++)
#pragma unroll
        for (int nt = 0; nt < 4; nt++)
#pragma unroll
            for (int rg = 0; rg < 4; rg++) {
                int m = row0 + wm + mt * 16 + quad * 4 + rg;
                int e = col0 + wn + nt * 16 + l16;
                float val = acc[mt][nt][rg];
                if (MODE == 0) {
                    float v2 = (val + bias[e]) * scale;
                    int n = m >> 2, bb = m & 3;
                    int h = e >> 6, d = e & 63;
                    out_bf[((((size_t)bb * H_DIM + h) * N_DIM + n) * D_DIM) + d] = (bf16)v2;
                } else {
                    out_f[(size_t)m * E_DIM + e] = val + bias[e];
                }
            }
}

// ---------------- Chunk stats: rf_k_bar, rfa_chunk per (b,h,c) ----------------
__global__ __launch_bounds__(128) void chunk_stats(
    const bf16* __restrict__ q_s, const bf16* __restrict__ kbuf, const bf16* __restrict__ vbuf,
    const float* __restrict__ mqw, const float* __restrict__ mqb,
    const float* __restrict__ mqg, const float* __restrict__ mqbe,
    const float* __restrict__ mkw, const float* __restrict__ mkb,
    const float* __restrict__ mkg, const float* __restrict__ mkbe,
    float* __restrict__ rf_k_bar, float* __restrict__ rfa_chunk)
{
    int bid = blockIdx.x;
    int c = bid % NC;
    int bh = bid / NC;           // b*H + h
    int tid = threadIdx.x;

    __shared__ float qm[64], km[64], qb_s[64], kb_s[64], mu_s[64], sc[128];
    __shared__ float stats[4];

    size_t base = ((size_t)bh * N_DIM + c * 128) * D_DIM;

    if (tid < 64) {
        float s = 0.f;
        for (int p = 0; p < 128; p++) s += (float)q_s[base + p * 64 + tid];
        qm[tid] = s * (1.0f / 128.0f);
    } else {
        int d = tid - 64;
        float s = 0.f;
        for (int p = 0; p < 128; p++) s += (float)kbuf[base + p * 64 + d];
        km[d] = s * (1.0f / 128.0f);
    }
    __syncthreads();

    if (tid < 64) {
        float t = mqb[tid];
        for (int d2 = 0; d2 < 64; d2++) t += qm[d2] * mqw[tid * 64 + d2];
        qb_s[tid] = t;
    } else {
        int d = tid - 64;
        float t = mkb[d];
        for (int d2 = 0; d2 < 64; d2++) t += km[d2] * mkw[d * 64 + d2];
        kb_s[d] = t;
    }
    __syncthreads();

    if (tid == 0) {
        float m = 0.f;
        for (int d = 0; d < 64; d++) m += qb_s[d];
        m *= (1.0f / 64.0f);
        float vv = 0.f;
        for (int d = 0; d < 64; d++) { float x = qb_s[d] - m; vv += x * x; }
        vv *= (1.0f / 64.0f);
        stats[0] = m; stats[1] = rsqrtf(vv + 1e-5f);
    } else if (tid == 64) {
        float m = 0.f;
        for (int d = 0; d < 64; d++) m += kb_s[d];
        m *= (1.0f / 64.0f);
        float vv = 0.f;
        for (int d = 0; d < 64; d++) { float x = kb_s[d] - m; vv += x * x; }
        vv *= (1.0f / 64.0f);
        stats[2] = m; stats[3] = rsqrtf(vv + 1e-5f);
    }
    __syncthreads();

    if (tid < 64) {
        float qn = (qb_s[tid] - stats[0]) * stats[1] * mqg[tid] + mqbe[tid];
        float kn = (kb_s[tid] - stats[2]) * stats[3] * mkg[tid] + mkbe[tid];
        mu_s[tid] = qn + kn;
        rf_k_bar[(size_t)bh * NC * 64 + c * 64 + tid] = kn;
    }
    __syncthreads();

    {
        float dot = 0.f, ss = 0.f;
        const bf16* kr = kbuf + base + tid * 64;
        for (int d = 0; d < 64; d++) {
            float kv = (float)kr[d];
            dot += mu_s[d] * kv;
            ss += kv * kv;
        }
        sc[tid] = dot * 0.125f - 0.125f * 0.5f * ss;
    }
    __syncthreads();
    if (tid == 0) {
        float m = sc[0];
        for (int p = 1; p < 128; p++) m = fmaxf(m, sc[p]);
        stats[0] = m;
    }
    __syncthreads();
    float e = expf(sc[tid] - stats[0]);
    sc[tid] = e;
    __syncthreads();
    if (tid == 0) {
        float s = 0.f;
        for (int p = 0; p < 128; p++) s += sc[p];
        stats[1] = 1.0f / s;
    }
    __syncthreads();
    sc[tid] *= stats[1];
    __syncthreads();

    if (tid < 64) {
        float acc = 0.f;
        for (int p = 0; p < 128; p++) acc += sc[p] * (float)vbuf[base + p * 64 + tid];
        rfa_chunk[(size_t)bh * NC * 64 + c * 64 + tid] = acc;
    }
}

// ---------------- Windowed attention per (b,h,g) — MFMA version --------------
__global__ __launch_bounds__(512, 2) void attn_kernel(
    const bf16* __restrict__ qin, const bf16* __restrict__ kbuf, const bf16* __restrict__ vbuf,
    const float* __restrict__ rf_k_bar, const float* __restrict__ rfa_chunk,
    bf16* __restrict__ aout)
{
    int bid = blockIdx.x;
    int g = bid & (G_WIN - 1);
    int bh = bid / G_WIN;          // b*H + h
    int b = bh >> 4, h = bh & 15;
    int tid = threadIdx.x;
    int lane = tid & 63;
    int wv = tid >> 6;             // 0..7
    int q4 = lane >> 4;            // 0..3
    int l16 = lane & 15;

    __shared__ __align__(16) short Ks[288 * 72];   // 41,472 B
    __shared__ __align__(16) short Vt[64 * 296];   // 37,888 B
    __shared__ __align__(16) short Pw[8 * 16 * 40]; // 10,240 B

    size_t kvbase = (size_t)bh * N_DIM * D_DIM;
    int k0g = g * 128 - 128;       // global key index of local j=0

    // ---- stage K local: 256 keys x 64 d (16B chunks, padded rows) ----
#pragma unroll
    for (int i = 0; i < 4; i++) {
        int ci = tid + i * 512;            // 0..2047
        int key = ci >> 3, chc = ci & 7;
        int kidx = k0g + key; if (kidx < 0) kidx = 0;   // masked later
        bf16x8 v = *(const bf16x8*)(kbuf + kvbase + (size_t)kidx * 64 + chc * 8);
        *(bf16x8*)(Ks + key * 72 + chc * 8) = v;
    }
    // ---- stage rf_k_bar (fp32 32x64) -> Ks rows 256..287 ----
    if (tid < 256) {
        int c = tid >> 3, chc = tid & 7;
        const float* src = rf_k_bar + (size_t)bh * NC * 64 + c * 64 + chc * 8;
        float4 f0 = *(const float4*)src;
        float4 f1 = *(const float4*)(src + 4);
        union { bf16 t[8]; bf16x8 v; } pk;
        pk.t[0] = (bf16)f0.x; pk.t[1] = (bf16)f0.y;
        pk.t[2] = (bf16)f0.z; pk.t[3] = (bf16)f0.w;
        pk.t[4] = (bf16)f1.x; pk.t[5] = (bf16)f1.y;
        pk.t[6] = (bf16)f1.z; pk.t[7] = (bf16)f1.w;
        *(bf16x8*)(Ks + (256 + c) * 72 + chc * 8) = pk.v;
    }
    // ---- stage V transposed: Vt[d][key] ----
#pragma unroll
    for (int i = 0; i < 4; i++) {
        int ci = tid + i * 512;            // 0..2047
        int key = ci & 255, dc = ci >> 8;  // dc 0..7
        int kidx = k0g + key; if (kidx < 0) kidx = 0;
        union { bf16x8 v; short s[8]; } u;
        u.v = *(const bf16x8*)(vbuf + kvbase + (size_t)kidx * 64 + dc * 8);
#pragma unroll
        for (int jj = 0; jj < 8; jj++)
            Vt[(dc * 8 + jj) * 296 + key] = u.s[jj];
    }
    // ---- stage rfa_chunk^T -> Vt key-cols 256..287 ----
    if (tid < 256) {
        int d = tid >> 2, cg = tid & 3;
        const float* rc = rfa_chunk + (size_t)bh * NC * 64;
#pragma unroll
        for (int jj = 0; jj < 8; jj++) {
            int c = cg * 8 + jj;
            union { bf16 bv; short s; } cv;
            cv.bv = (bf16)rc[(size_t)c * 64 + d];
            Vt[d * 296 + 256 + c] = cv.s;
        }
    }

    // ---- Q fragments (global, rows are wave-private) ----
    bf16x8 aq[2];
    {
        const bf16* qrow = qin + kvbase + (size_t)(g * 128 + wv * 16 + l16) * 64 + q4 * 8;
        aq[0] = *(const bf16x8*)qrow;
        aq[1] = *(const bf16x8*)(qrow + 32);
    }

    __syncthreads();

    // ---- QK^T: S[16 x 288] per wave, in registers ----
    f32x4 acc[18] = {};
#pragma unroll
    for (int ct = 0; ct < 18; ct++) {
#pragma unroll
        for (int kc = 0; kc < 2; kc++) {
            bf16x8 bk = *(const bf16x8*)(Ks + (ct * 16 + l16) * 72 + kc * 32 + q4 * 8);
            acc[ct] = __builtin_amdgcn_mfma_f32_16x16x32_bf16(aq[kc], bk, acc[ct], 0, 0, 0);
        }
    }

    // ---- mask + row max ----
    float mrow[4] = { -1e30f, -1e30f, -1e30f, -1e30f };
#pragma unroll
    for (int ct = 0; ct < 18; ct++) {
        int j = ct * 16 + l16;
        bool jval = (j < 256) ? (k0g + j >= 0) : ((j - 256) < g);
#pragma unroll
        for (int rg = 0; rg < 4; rg++) {
            int i = wv * 16 + q4 * 4 + rg;              // row within window
            bool ok = jval && (j >= 256 || j <= i + 128);
            float s = ok ? acc[ct][rg] : -1e9f;
            acc[ct][rg] = s;
            mrow[rg] = fmaxf(mrow[rg], s);
        }
    }
#pragma unroll
    for (int rg = 0; rg < 4; rg++) {
        float v = mrow[rg];
        v = fmaxf(v, __shfl_xor(v, 1));
        v = fmaxf(v, __shfl_xor(v, 2));
        v = fmaxf(v, __shfl_xor(v, 4));
        v = fmaxf(v, __shfl_xor(v, 8));
        mrow[rg] = v;
    }

    // ---- exp + row sum (normalization deferred to epilogue) ----
    float rsum[4] = { 0.f, 0.f, 0.f, 0.f };
#pragma unroll
    for (int ct = 0; ct < 18; ct++)
#pragma unroll
        for (int rg = 0; rg < 4; rg++) {
            float p = __expf(acc[ct][rg] - mrow[rg]);
            acc[ct][rg] = p;
            rsum[rg] += p;
        }
    float rinv[4];
#pragma unroll
    for (int rg = 0; rg < 4; rg++) {
        float v = rsum[rg];
        v += __shfl_xor(v, 1);
        v += __shfl_xor(v, 2);
        v += __shfl_xor(v, 4);
        v += __shfl_xor(v, 8);
        rinv[rg] = 1.0f / v;
    }

    // ---- P·V: transpose P through wave-private LDS scratch, MFMA ----
    f32x4 accO[4] = {};
    short* pw = Pw + wv * (16 * 40);
#pragma unroll
    for (int cc = 0; cc < 9; cc++) {
#pragma unroll
        for (int half = 0; half < 2; half++) {
            int ct = cc * 2 + half;
#pragma unroll
            for (int rg = 0; rg < 4; rg++) {
                union { bf16 bv; short s; } cv;
                cv.bv = (bf16)acc[ct][rg];
                pw[(q4 * 4 + rg) * 40 + half * 16 + l16] = cv.s;
            }
        }
        bf16x8 ap = *(const bf16x8*)(pw + l16 * 40 + q4 * 8);
#pragma unroll
        for (int dt = 0; dt < 4; dt++) {
            bf16x8 bv = *(const bf16x8*)(Vt + (dt * 16 + l16) * 296 + cc * 32 + q4 * 8);
            accO[dt] = __builtin_amdgcn_mfma_f32_16x16x32_bf16(ap, bv, accO[dt], 0, 0, 0);
        }
    }

    // ---- epilogue: normalize, store row-major [n*B + b][h*64 + d] ----
    int nbase = g * 128 + wv * 16 + q4 * 4;
#pragma unroll
    for (int dt = 0; dt < 4; dt++)
#pragma unroll
        for (int rg = 0; rg < 4; rg++) {
            float o = accO[dt][rg] * rinv[rg];
            int nn = nbase + rg;
            int d = dt * 16 + l16;
            aout[((size_t)nn * B_DIM + b) * E_DIM + h * 64 + d] = (bf16)o;
        }
}

extern "C" void kernel_launch(void* const* d_in, const int* in_sizes, int n_in,
                              void* d_out, int out_size, void* d_ws, size_t ws_size,
                              hipStream_t stream) {
    const float* query = (const float*)d_in[0];
    const float* Wq   = (const float*)d_in[1];
    const float* bq   = (const float*)d_in[2];
    const float* Wk   = (const float*)d_in[3];
    const float* bk   = (const float*)d_in[4];
    const float* Wv   = (const float*)d_in[5];
    const float* bv   = (const float*)d_in[6];
    const float* Wo   = (const float*)d_in[7];
    const float* bo   = (const float*)d_in[8];
    const float* mqw  = (const float*)d_in[9];
    const float* mqb  = (const float*)d_in[10];
    const float* mqg  = (const float*)d_in[11];
    const float* mqbe = (const float*)d_in[12];
    const float* mkw  = (const float*)d_in[13];
    const float* mkb  = (const float*)d_in[14];
    const float* mkg  = (const float*)d_in[15];
    const float* mkbe = (const float*)d_in[16];

    const size_t SZ = (size_t)B_DIM * H_DIM * N_DIM * D_DIM; // 16,777,216 elems
    const size_t STATS = (size_t)B_DIM * H_DIM * NC * D_DIM; // 131,072 elems

    // ws layout: k,v bf16 (64 MiB) + fp32 stats (1 MiB) [proven 65 MiB]
    //            + optional 8 MiB bf16 weights if ws_size allows
    bf16* kb = (bf16*)d_ws;
    bf16* vb = kb + SZ;
    float* rf_k_bar  = (float*)(vb + SZ);
    float* rfa_chunk = rf_k_bar + STATS;

    size_t base_bytes = 2 * SZ * sizeof(bf16) + 2 * STATS * sizeof(float);
    size_t wmat = (size_t)E_DIM * E_DIM;               // elems per weight matrix
    bool wb16 = ws_size >= base_bytes + 4 * wmat * sizeof(bf16);
    bf16* wq_b = (bf16*)((char*)d_ws + base_bytes);
    bf16* wk_b = wq_b + wmat;
    bf16* wv_b = wk_b + wmat;
    bf16* wo_b = wv_b + wmat;

    // d_out (64 MiB fp32): half1 = q bf16 [B,H,N,D]; half2 = query_bf16, later attn-out bf16.
    float* outf = (float*)d_out;
    bf16* qb  = (bf16*)d_out;      // 32 MiB
    bf16* qbf = qb + SZ;           // 32 MiB: query in bf16, then attn output

    dim3 gblk(256);
    int ggrd = (E_DIM / 128) * (M_ROWS / 128);   // 1024 blocks, 1-D + swizzle

    // 1. query fp32 -> bf16 (and weights, if workspace allows)
    cvt_f32_bf16<<<(M_ROWS * E_DIM) / (256 * 8), 256, 0, stream>>>(query, qbf);
    if (wb16) {
        int wblk = (int)(wmat / (256 * 8));   // 512
        cvt_f32_bf16<<<wblk, 256, 0, stream>>>(Wq, wq_b);
        cvt_f32_bf16<<<wblk, 256, 0, stream>>>(Wk, wk_b);
        cvt_f32_bf16<<<wblk, 256, 0, stream>>>(Wv, wv_b);
        cvt_f32_bf16<<<wblk, 256, 0, stream>>>(Wo, wo_b);
    }

    // 2. projections (MFMA)
    if (wb16) {
        gemm_mfma<0, true><<<ggrd, gblk, 0, stream>>>(qbf, wq_b, bq, 0.125f, qb, nullptr);
        gemm_mfma<0, true><<<ggrd, gblk, 0, stream>>>(qbf, wk_b, bk, 1.0f, kb, nullptr);
        gemm_mfma<0, true><<<ggrd, gblk, 0, stream>>>(qbf, wv_b, bv, 1.0f, vb, nullptr);
    } else {
        gemm_mfma<0, false><<<ggrd, gblk, 0, stream>>>(qbf, Wq, bq, 0.125f, qb, nullptr);
        gemm_mfma<0, false><<<ggrd, gblk, 0, stream>>>(qbf, Wk, bk, 1.0f, kb, nullptr);
        gemm_mfma<0, false><<<ggrd, gblk, 0, stream>>>(qbf, Wv, bv, 1.0f, vb, nullptr);
    }

    // 3. chunk stats
    chunk_stats<<<B_DIM * H_DIM * NC, 128, 0, stream>>>(
        qb, kb, vb, mqw, mqb, mqg, mqbe, mkw, mkb, mkg, mkbe, rf_k_bar, rfa_chunk);

    // 4. attention (MFMA) -> qbf region (query_bf dead), row-major [N*B][E] bf16
    attn_kernel<<<B_DIM * H_DIM * G_WIN, 512, 0, stream>>>(
        qb, kb, vb, rf_k_bar, rfa_chunk, qbf);

    // 5. stage attn output into kb (dead) so final GEMM doesn't read d_out
    (void)hipMemcpyAsync(kb, qbf, SZ * sizeof(bf16), hipMemcpyDeviceToDevice, stream);

    // 6. output projection (MFMA), fp32 out over all of d_out
    if (wb16) {
        gemm_mfma<1, true><<<ggrd, gblk, 0, stream>>>(kb, wo_b, bo, 1.0f, nullptr, outf);
    } else {
        gemm_mfma<1, false><<<ggrd, gblk, 0, stream>>>(kb, Wo, bo, 1.0f, nullptr, outf);
    }
}

// Round 4
// 432.885 us; speedup vs baseline: 10.1347x; 1.0514x over previous
//
#include <hip/hip_runtime.h>
#include <hip/hip_bf16.h>

typedef __hip_bfloat16 bf16;
typedef __attribute__((ext_vector_type(8))) short bf16x8;
typedef __attribute__((ext_vector_type(4))) float f32x4;

#define E_DIM 1024
#define H_DIM 16
#define N_DIM 4096
#define B_DIM 4
#define D_DIM 64
#define G_WIN 32   // N / 128
#define NC 32      // N / 128
#define M_ROWS 16384  // N*B

// ---------------- fp32 -> bf16 bulk convert (8 elems/thread) ----------------
__global__ __launch_bounds__(256) void cvt_f32_bf16(
    const float* __restrict__ in, bf16* __restrict__ out)
{
    int i = (blockIdx.x * 256 + threadIdx.x) * 8;
    float4 f0 = *(const float4*)(in + i);
    float4 f1 = *(const float4*)(in + i + 4);
    union { bf16 t[8]; uint4 u; } pk;
    pk.t[0] = (bf16)f0.x; pk.t[1] = (bf16)f0.y; pk.t[2] = (bf16)f0.z; pk.t[3] = (bf16)f0.w;
    pk.t[4] = (bf16)f1.x; pk.t[5] = (bf16)f1.y; pk.t[6] = (bf16)f1.z; pk.t[7] = (bf16)f1.w;
    *(uint4*)(out + i) = pk.u;
}

// ---------------- MFMA GEMM ----------------
// out[m,e] = sum_k A[m,k] * W[e,k]  (A bf16 row-major [M][K])
// 128x128 tile, 4 waves of 64x64, mfma_f32_16x16x32_bf16, BK=32.
// 1-D grid with chunked XCD swizzle; col-fastest tiles.
// WB16: W is pre-converted bf16 [e][k] (global_load_lds staging, no VALU).
// MODE 0: (val + bias)*scale -> bf16 scatter [B,H,N,D]   (m=n*B+b, e=h*64+d)
// MODE 1: val + bias -> fp32 row-major [M][E]
template<int MODE, bool WB16>
__global__ __launch_bounds__(256) void gemm_mfma(
    const bf16* __restrict__ A, const void* __restrict__ Wp,
    const float* __restrict__ bias, float scale,
    bf16* __restrict__ out_bf, float* __restrict__ out_f)
{
    __shared__ bf16 As[128 * 32];
    __shared__ bf16 Bs[128 * 32];
    int tid  = threadIdx.x;
    int lane = tid & 63;
    int wv   = tid >> 6;
    int wm   = (wv >> 1) * 64;
    int wn   = (wv & 1) * 64;
    int quad = lane >> 4;
    int l16  = lane & 15;

    // XCD-chunked swizzle (nwg divisible by 8)
    int nwg = gridDim.x;
    int per = nwg >> 3;
    int logical = (blockIdx.x & 7) * per + (blockIdx.x >> 3);
    int col0 = (logical & 7) * 128;      // 8 col tiles (E=1024)
    int row0 = (logical >> 3) * 128;

    f32x4 acc[4][4] = {};

    for (int k0 = 0; k0 < E_DIM; k0 += 32) {
        // A tile: 128 rows x 32 cols bf16 via global_load_lds (16B per lane)
#pragma unroll
        for (int i = 0; i < 2; i++) {
            int idx = tid + i * 256;
            int r = idx >> 2, c = idx & 3;
            const bf16* g = A + (size_t)(row0 + r) * E_DIM + k0 + c * 8;
            __builtin_amdgcn_global_load_lds(
                (const __attribute__((address_space(1))) void*)g,
                (__attribute__((address_space(3))) void*)(As + idx * 8), 16, 0, 0);
        }
        if constexpr (WB16) {
            const bf16* Wb = (const bf16*)Wp;
#pragma unroll
            for (int i = 0; i < 2; i++) {
                int idx = tid + i * 256;
                int e = idx >> 2, c = idx & 3;
                const bf16* g = Wb + (size_t)(col0 + e) * E_DIM + k0 + c * 8;
                __builtin_amdgcn_global_load_lds(
                    (const __attribute__((address_space(1))) void*)g,
                    (__attribute__((address_space(3))) void*)(Bs + idx * 8), 16, 0, 0);
            }
        } else {
            const float* Wf = (const float*)Wp;
#pragma unroll
            for (int i = 0; i < 2; i++) {
                int idx = tid + i * 256;
                int e = idx >> 2, c = idx & 3;
                const float* wr = Wf + (size_t)(col0 + e) * E_DIM + k0 + c * 8;
                float4 f0 = *(const float4*)wr;
                float4 f1 = *(const float4*)(wr + 4);
                union { bf16 t[8]; uint4 u; } pk;
                pk.t[0] = (bf16)f0.x; pk.t[1] = (bf16)f0.y;
                pk.t[2] = (bf16)f0.z; pk.t[3] = (bf16)f0.w;
                pk.t[4] = (bf16)f1.x; pk.t[5] = (bf16)f1.y;
                pk.t[6] = (bf16)f1.z; pk.t[7] = (bf16)f1.w;
                *(uint4*)(Bs + idx * 8) = pk.u;
            }
        }
        __syncthreads();

        bf16x8 af[4], bfr[4];
#pragma unroll
        for (int t = 0; t < 4; t++) {
            af[t]  = *(const bf16x8*)(As + (wm + t * 16 + l16) * 32 + quad * 8);
            bfr[t] = *(const bf16x8*)(Bs + (wn + t * 16 + l16) * 32 + quad * 8);
        }
#pragma unroll
        for (int mt = 0; mt < 4; mt++)
#pragma unroll
            for (int nt = 0; nt < 4; nt++)
                acc[mt][nt] = __builtin_amdgcn_mfma_f32_16x16x32_bf16(
                    af[mt], bfr[nt], acc[mt][nt], 0, 0, 0);
        __syncthreads();
    }

#pragma unroll
    for (int mt = 0; mt < 4; mt++)
#pragma unroll
        for (int nt = 0; nt < 4; nt++)
#pragma unroll
            for (int rg = 0; rg < 4; rg++) {
                int m = row0 + wm + mt * 16 + quad * 4 + rg;
                int e = col0 + wn + nt * 16 + l16;
                float val = acc[mt][nt][rg];
                if (MODE == 0) {
                    float v2 = (val + bias[e]) * scale;
                    int n = m >> 2, bb = m & 3;
                    int h = e >> 6, d = e & 63;
                    out_bf[((((size_t)bb * H_DIM + h) * N_DIM + n) * D_DIM) + d] = (bf16)v2;
                } else {
                    out_f[(size_t)m * E_DIM + e] = val + bias[e];
                }
            }
}

// ---------------- Chunk stats: rf_k_bar, rfa_chunk per (b,h,c) ----------------
__global__ __launch_bounds__(128) void chunk_stats(
    const bf16* __restrict__ q_s, const bf16* __restrict__ kbuf, const bf16* __restrict__ vbuf,
    const float* __restrict__ mqw, const float* __restrict__ mqb,
    const float* __restrict__ mqg, const float* __restrict__ mqbe,
    const float* __restrict__ mkw, const float* __restrict__ mkb,
    const float* __restrict__ mkg, const float* __restrict__ mkbe,
    float* __restrict__ rf_k_bar, float* __restrict__ rfa_chunk)
{
    int bid = blockIdx.x;
    int c = bid % NC;
    int bh = bid / NC;           // b*H + h
    int tid = threadIdx.x;

    __shared__ float qm[64], km[64], qb_s[64], kb_s[64], mu_s[64], sc[128];
    __shared__ float stats[4];

    size_t base = ((size_t)bh * N_DIM + c * 128) * D_DIM;

    if (tid < 64) {
        float s = 0.f;
        for (int p = 0; p < 128; p++) s += (float)q_s[base + p * 64 + tid];
        qm[tid] = s * (1.0f / 128.0f);
    } else {
        int d = tid - 64;
        float s = 0.f;
        for (int p = 0; p < 128; p++) s += (float)kbuf[base + p * 64 + d];
        km[d] = s * (1.0f / 128.0f);
    }
    __syncthreads();

    if (tid < 64) {
        float t = mqb[tid];
        for (int d2 = 0; d2 < 64; d2++) t += qm[d2] * mqw[tid * 64 + d2];
        qb_s[tid] = t;
    } else {
        int d = tid - 64;
        float t = mkb[d];
        for (int d2 = 0; d2 < 64; d2++) t += km[d2] * mkw[d * 64 + d2];
        kb_s[d] = t;
    }
    __syncthreads();

    if (tid == 0) {
        float m = 0.f;
        for (int d = 0; d < 64; d++) m += qb_s[d];
        m *= (1.0f / 64.0f);
        float vv = 0.f;
        for (int d = 0; d < 64; d++) { float x = qb_s[d] - m; vv += x * x; }
        vv *= (1.0f / 64.0f);
        stats[0] = m; stats[1] = rsqrtf(vv + 1e-5f);
    } else if (tid == 64) {
        float m = 0.f;
        for (int d = 0; d < 64; d++) m += kb_s[d];
        m *= (1.0f / 64.0f);
        float vv = 0.f;
        for (int d = 0; d < 64; d++) { float x = kb_s[d] - m; vv += x * x; }
        vv *= (1.0f / 64.0f);
        stats[2] = m; stats[3] = rsqrtf(vv + 1e-5f);
    }
    __syncthreads();

    if (tid < 64) {
        float qn = (qb_s[tid] - stats[0]) * stats[1] * mqg[tid] + mqbe[tid];
        float kn = (kb_s[tid] - stats[2]) * stats[3] * mkg[tid] + mkbe[tid];
        mu_s[tid] = qn + kn;
        rf_k_bar[(size_t)bh * NC * 64 + c * 64 + tid] = kn;
    }
    __syncthreads();

    {
        float dot = 0.f, ss = 0.f;
        const bf16* kr = kbuf + base + tid * 64;
        for (int d = 0; d < 64; d++) {
            float kv = (float)kr[d];
            dot += mu_s[d] * kv;
            ss += kv * kv;
        }
        sc[tid] = dot * 0.125f - 0.125f * 0.5f * ss;
    }
    __syncthreads();
    if (tid == 0) {
        float m = sc[0];
        for (int p = 1; p < 128; p++) m = fmaxf(m, sc[p]);
        stats[0] = m;
    }
    __syncthreads();
    float e = expf(sc[tid] - stats[0]);
    sc[tid] = e;
    __syncthreads();
    if (tid == 0) {
        float s = 0.f;
        for (int p = 0; p < 128; p++) s += sc[p];
        stats[1] = 1.0f / s;
    }
    __syncthreads();
    sc[tid] *= stats[1];
    __syncthreads();

    if (tid < 64) {
        float acc = 0.f;
        for (int p = 0; p < 128; p++) acc += sc[p] * (float)vbuf[base + p * 64 + tid];
        rfa_chunk[(size_t)bh * NC * 64 + c * 64 + tid] = acc;
    }
}

// ---------------- Windowed attention per (b,h,g) — MFMA version --------------
// LDS trimmed to 79,360 B (< 80 KB) so 2 blocks fit per CU: the P-transpose
// scratch is overlaid on Ks (dead after the QK^T MFMA loop; one extra
// __syncthreads() separates the last Ks read from the first Pw write).
__global__ __launch_bounds__(512, 4) void attn_kernel(
    const bf16* __restrict__ qin, const bf16* __restrict__ kbuf, const bf16* __restrict__ vbuf,
    const float* __restrict__ rf_k_bar, const float* __restrict__ rfa_chunk,
    bf16* __restrict__ aout)
{
    int bid = blockIdx.x;
    int g = bid & (G_WIN - 1);
    int bh = bid / G_WIN;          // b*H + h
    int b = bh >> 4, h = bh & 15;
    int tid = threadIdx.x;
    int lane = tid & 63;
    int wv = tid >> 6;             // 0..7
    int q4 = lane >> 4;            // 0..3
    int l16 = lane & 15;

    __shared__ __align__(16) short Ks[288 * 72];   // 41,472 B (reused as Pw)
    __shared__ __align__(16) short Vt[64 * 296];   // 37,888 B

    size_t kvbase = (size_t)bh * N_DIM * D_DIM;
    int k0g = g * 128 - 128;       // global key index of local j=0

    // ---- stage K local: 256 keys x 64 d (16B chunks, padded rows) ----
#pragma unroll
    for (int i = 0; i < 4; i++) {
        int ci = tid + i * 512;            // 0..2047
        int key = ci >> 3, chc = ci & 7;
        int kidx = k0g + key; if (kidx < 0) kidx = 0;   // masked later
        bf16x8 v = *(const bf16x8*)(kbuf + kvbase + (size_t)kidx * 64 + chc * 8);
        *(bf16x8*)(Ks + key * 72 + chc * 8) = v;
    }
    // ---- stage rf_k_bar (fp32 32x64) -> Ks rows 256..287 ----
    if (tid < 256) {
        int c = tid >> 3, chc = tid & 7;
        const float* src = rf_k_bar + (size_t)bh * NC * 64 + c * 64 + chc * 8;
        float4 f0 = *(const float4*)src;
        float4 f1 = *(const float4*)(src + 4);
        union { bf16 t[8]; bf16x8 v; } pk;
        pk.t[0] = (bf16)f0.x; pk.t[1] = (bf16)f0.y;
        pk.t[2] = (bf16)f0.z; pk.t[3] = (bf16)f0.w;
        pk.t[4] = (bf16)f1.x; pk.t[5] = (bf16)f1.y;
        pk.t[6] = (bf16)f1.z; pk.t[7] = (bf16)f1.w;
        *(bf16x8*)(Ks + (256 + c) * 72 + chc * 8) = pk.v;
    }
    // ---- stage V transposed: Vt[d][key] ----
#pragma unroll
    for (int i = 0; i < 4; i++) {
        int ci = tid + i * 512;            // 0..2047
        int key = ci & 255, dc = ci >> 8;  // dc 0..7
        int kidx = k0g + key; if (kidx < 0) kidx = 0;
        union { bf16x8 v; short s[8]; } u;
        u.v = *(const bf16x8*)(vbuf + kvbase + (size_t)kidx * 64 + dc * 8);
#pragma unroll
        for (int jj = 0; jj < 8; jj++)
            Vt[(dc * 8 + jj) * 296 + key] = u.s[jj];
    }
    // ---- stage rfa_chunk^T -> Vt key-cols 256..287 ----
    if (tid < 256) {
        int d = tid >> 2, cg = tid & 3;
        const float* rc = rfa_chunk + (size_t)bh * NC * 64;
#pragma unroll
        for (int jj = 0; jj < 8; jj++) {
            int c = cg * 8 + jj;
            union { bf16 bv; short s; } cv;
            cv.bv = (bf16)rc[(size_t)c * 64 + d];
            Vt[d * 296 + 256 + c] = cv.s;
        }
    }

    // ---- Q fragments (global, rows are wave-private) ----
    bf16x8 aq[2];
    {
        const bf16* qrow = qin + kvbase + (size_t)(g * 128 + wv * 16 + l16) * 64 + q4 * 8;
        aq[0] = *(const bf16x8*)qrow;
        aq[1] = *(const bf16x8*)(qrow + 32);
    }

    __syncthreads();

    // ---- QK^T: S[16 x 288] per wave, in registers ----
    f32x4 acc[18] = {};
#pragma unroll
    for (int ct = 0; ct < 18; ct++) {
#pragma unroll
        for (int kc = 0; kc < 2; kc++) {
            bf16x8 bk = *(const bf16x8*)(Ks + (ct * 16 + l16) * 72 + kc * 32 + q4 * 8);
            acc[ct] = __builtin_amdgcn_mfma_f32_16x16x32_bf16(aq[kc], bk, acc[ct], 0, 0, 0);
        }
    }

    // Ks is dead from here; all waves must pass this point before Pw overlay.
    __syncthreads();

    // ---- mask + row max ----
    float mrow[4] = { -1e30f, -1e30f, -1e30f, -1e30f };
#pragma unroll
    for (int ct = 0; ct < 18; ct++) {
        int j = ct * 16 + l16;
        bool jval = (j < 256) ? (k0g + j >= 0) : ((j - 256) < g);
#pragma unroll
        for (int rg = 0; rg < 4; rg++) {
            int i = wv * 16 + q4 * 4 + rg;              // row within window
            bool ok = jval && (j >= 256 || j <= i + 128);
            float s = ok ? acc[ct][rg] : -1e9f;
            acc[ct][rg] = s;
            mrow[rg] = fmaxf(mrow[rg], s);
        }
    }
#pragma unroll
    for (int rg = 0; rg < 4; rg++) {
        float v = mrow[rg];
        v = fmaxf(v, __shfl_xor(v, 1));
        v = fmaxf(v, __shfl_xor(v, 2));
        v = fmaxf(v, __shfl_xor(v, 4));
        v = fmaxf(v, __shfl_xor(v, 8));
        mrow[rg] = v;
    }

    // ---- exp + row sum (normalization deferred to epilogue) ----
    float rsum[4] = { 0.f, 0.f, 0.f, 0.f };
#pragma unroll
    for (int ct = 0; ct < 18; ct++)
#pragma unroll
        for (int rg = 0; rg < 4; rg++) {
            float p = __expf(acc[ct][rg] - mrow[rg]);
            acc[ct][rg] = p;
            rsum[rg] += p;
        }
    float rinv[4];
#pragma unroll
    for (int rg = 0; rg < 4; rg++) {
        float v = rsum[rg];
        v += __shfl_xor(v, 1);
        v += __shfl_xor(v, 2);
        v += __shfl_xor(v, 4);
        v += __shfl_xor(v, 8);
        rinv[rg] = 1.0f / v;
    }

    // ---- P·V: transpose P through wave-private scratch overlaid on Ks ----
    f32x4 accO[4] = {};
    short* pw = Ks + wv * (16 * 40);
#pragma unroll
    for (int cc = 0; cc < 9; cc++) {
#pragma unroll
        for (int half = 0; half < 2; half++) {
            int ct = cc * 2 + half;
#pragma unroll
            for (int rg = 0; rg < 4; rg++) {
                union { bf16 bv; short s; } cv;
                cv.bv = (bf16)acc[ct][rg];
                pw[(q4 * 4 + rg) * 40 + half * 16 + l16] = cv.s;
            }
        }
        bf16x8 ap = *(const bf16x8*)(pw + l16 * 40 + q4 * 8);
#pragma unroll
        for (int dt = 0; dt < 4; dt++) {
            bf16x8 bv = *(const bf16x8*)(Vt + (dt * 16 + l16) * 296 + cc * 32 + q4 * 8);
            accO[dt] = __builtin_amdgcn_mfma_f32_16x16x32_bf16(ap, bv, accO[dt], 0, 0, 0);
        }
    }

    // ---- epilogue: normalize, store row-major [n*B + b][h*64 + d] ----
    int nbase = g * 128 + wv * 16 + q4 * 4;
#pragma unroll
    for (int dt = 0; dt < 4; dt++)
#pragma unroll
        for (int rg = 0; rg < 4; rg++) {
            float o = accO[dt][rg] * rinv[rg];
            int nn = nbase + rg;
            int d = dt * 16 + l16;
            aout[((size_t)nn * B_DIM + b) * E_DIM + h * 64 + d] = (bf16)o;
        }
}

extern "C" void kernel_launch(void* const* d_in, const int* in_sizes, int n_in,
                              void* d_out, int out_size, void* d_ws, size_t ws_size,
                              hipStream_t stream) {
    const float* query = (const float*)d_in[0];
    const float* Wq   = (const float*)d_in[1];
    const float* bq   = (const float*)d_in[2];
    const float* Wk   = (const float*)d_in[3];
    const float* bk   = (const float*)d_in[4];
    const float* Wv   = (const float*)d_in[5];
    const float* bv   = (const float*)d_in[6];
    const float* Wo   = (const float*)d_in[7];
    const float* bo   = (const float*)d_in[8];
    const float* mqw  = (const float*)d_in[9];
    const float* mqb  = (const float*)d_in[10];
    const float* mqg  = (const float*)d_in[11];
    const float* mqbe = (const float*)d_in[12];
    const float* mkw  = (const float*)d_in[13];
    const float* mkb  = (const float*)d_in[14];
    const float* mkg  = (const float*)d_in[15];
    const float* mkbe = (const float*)d_in[16];

    const size_t SZ = (size_t)B_DIM * H_DIM * N_DIM * D_DIM; // 16,777,216 elems
    const size_t STATS = (size_t)B_DIM * H_DIM * NC * D_DIM; // 131,072 elems

    // ws layout: k,v bf16 (64 MiB) + fp32 stats (1 MiB) [proven]
    //            + 8 MiB bf16 weights (tier 1) + 32 MiB attn-out (tier 2)
    bf16* kb = (bf16*)d_ws;
    bf16* vb = kb + SZ;
    float* rf_k_bar  = (float*)(vb + SZ);
    float* rfa_chunk = rf_k_bar + STATS;

    size_t base_bytes = 2 * SZ * sizeof(bf16) + 2 * STATS * sizeof(float);
    size_t wmat = (size_t)E_DIM * E_DIM;               // elems per weight matrix
    bool wb16   = ws_size >= base_bytes + 4 * wmat * sizeof(bf16);
    bool big_ws = ws_size >= base_bytes + 4 * wmat * sizeof(bf16) + SZ * sizeof(bf16);
    bf16* wq_b = (bf16*)((char*)d_ws + base_bytes);
    bf16* wk_b = wq_b + wmat;
    bf16* wv_b = wk_b + wmat;
    bf16* wo_b = wv_b + wmat;
    bf16* att_ws = wo_b + wmat;    // tier-2 attn output (row-major [M][E] bf16)

    // d_out (64 MiB fp32): half1 = q bf16 [B,H,N,D]; half2 = query_bf16 (+ attn-out fallback).
    float* outf = (float*)d_out;
    bf16* qb  = (bf16*)d_out;      // 32 MiB
    bf16* qbf = qb + SZ;           // 32 MiB

    dim3 gblk(256);
    int ggrd = (E_DIM / 128) * (M_ROWS / 128);   // 1024 blocks, 1-D + swizzle

    // 1. query fp32 -> bf16 (and weights, if workspace allows)
    cvt_f32_bf16<<<(M_ROWS * E_DIM) / (256 * 8), 256, 0, stream>>>(query, qbf);
    if (wb16) {
        int wblk = (int)(wmat / (256 * 8));   // 512
        cvt_f32_bf16<<<wblk, 256, 0, stream>>>(Wq, wq_b);
        cvt_f32_bf16<<<wblk, 256, 0, stream>>>(Wk, wk_b);
        cvt_f32_bf16<<<wblk, 256, 0, stream>>>(Wv, wv_b);
        cvt_f32_bf16<<<wblk, 256, 0, stream>>>(Wo, wo_b);
    }

    // 2. projections (MFMA)
    if (wb16) {
        gemm_mfma<0, true><<<ggrd, gblk, 0, stream>>>(qbf, wq_b, bq, 0.125f, qb, nullptr);
        gemm_mfma<0, true><<<ggrd, gblk, 0, stream>>>(qbf, wk_b, bk, 1.0f, kb, nullptr);
        gemm_mfma<0, true><<<ggrd, gblk, 0, stream>>>(qbf, wv_b, bv, 1.0f, vb, nullptr);
    } else {
        gemm_mfma<0, false><<<ggrd, gblk, 0, stream>>>(qbf, Wq, bq, 0.125f, qb, nullptr);
        gemm_mfma<0, false><<<ggrd, gblk, 0, stream>>>(qbf, Wk, bk, 1.0f, kb, nullptr);
        gemm_mfma<0, false><<<ggrd, gblk, 0, stream>>>(qbf, Wv, bv, 1.0f, vb, nullptr);
    }

    // 3. chunk stats
    chunk_stats<<<B_DIM * H_DIM * NC, 128, 0, stream>>>(
        qb, kb, vb, mqw, mqb, mqg, mqbe, mkw, mkb, mkg, mkbe, rf_k_bar, rfa_chunk);

    // 4. attention (MFMA): big_ws -> write straight into ws, no memcpy needed
    bf16* attn_dst = big_ws ? att_ws : qbf;
    attn_kernel<<<B_DIM * H_DIM * G_WIN, 512, 0, stream>>>(
        qb, kb, vb, rf_k_bar, rfa_chunk, attn_dst);

    const bf16* gemm_in;
    if (big_ws) {
        gemm_in = att_ws;
    } else {
        // stage attn output into kb (dead) so final GEMM doesn't read d_out
        (void)hipMemcpyAsync(kb, qbf, SZ * sizeof(bf16), hipMemcpyDeviceToDevice, stream);
        gemm_in = kb;
    }

    // 6. output projection (MFMA), fp32 out over all of d_out
    if (wb16) {
        gemm_mfma<1, true><<<ggrd, gblk, 0, stream>>>(gemm_in, wo_b, bo, 1.0f, nullptr, outf);
    } else {
        gemm_mfma<1, false><<<ggrd, gblk, 0, stream>>>(gemm_in, Wo, bo, 1.0f, nullptr, outf);
    }
}

// Round 6
// 424.079 us; speedup vs baseline: 10.3451x; 1.0208x over previous
//
#include <hip/hip_runtime.h>
#include <hip/hip_bf16.h>

typedef __hip_bfloat16 bf16;
typedef __attribute__((ext_vector_type(8))) short bf16x8;
typedef __attribute__((ext_vector_type(4))) float f32x4;

#define E_DIM 1024
#define H_DIM 16
#define N_DIM 4096
#define B_DIM 4
#define D_DIM 64
#define G_WIN 32   // N / 128
#define NC 32      // N / 128
#define M_ROWS 16384  // N*B

#define AS1 __attribute__((address_space(1)))
#define AS3 __attribute__((address_space(3)))

// ---------------- fp32 -> bf16 bulk convert (8 elems/thread) ----------------
__global__ __launch_bounds__(256) void cvt_f32_bf16(
    const float* __restrict__ in, bf16* __restrict__ out)
{
    int i = (blockIdx.x * 256 + threadIdx.x) * 8;
    float4 f0 = *(const float4*)(in + i);
    float4 f1 = *(const float4*)(in + i + 4);
    union { bf16 t[8]; uint4 u; } pk;
    pk.t[0] = (bf16)f0.x; pk.t[1] = (bf16)f0.y; pk.t[2] = (bf16)f0.z; pk.t[3] = (bf16)f0.w;
    pk.t[4] = (bf16)f1.x; pk.t[5] = (bf16)f1.y; pk.t[6] = (bf16)f1.z; pk.t[7] = (bf16)f1.w;
    *(uint4*)(out + i) = pk.u;
}

// ---------------- MFMA GEMM (unchanged from round 4) ----------------
template<int MODE, bool WB16>
__global__ __launch_bounds__(256) void gemm_mfma(
    const bf16* __restrict__ A, const void* __restrict__ Wp,
    const float* __restrict__ bias, float scale,
    bf16* __restrict__ out_bf, float* __restrict__ out_f)
{
    __shared__ bf16 As[128 * 32];
    __shared__ bf16 Bs[128 * 32];
    int tid  = threadIdx.x;
    int lane = tid & 63;
    int wv   = tid >> 6;
    int wm   = (wv >> 1) * 64;
    int wn   = (wv & 1) * 64;
    int quad = lane >> 4;
    int l16  = lane & 15;

    int nwg = gridDim.x;
    int per = nwg >> 3;
    int logical = (blockIdx.x & 7) * per + (blockIdx.x >> 3);
    int col0 = (logical & 7) * 128;
    int row0 = (logical >> 3) * 128;

    f32x4 acc[4][4] = {};

    for (int k0 = 0; k0 < E_DIM; k0 += 32) {
#pragma unroll
        for (int i = 0; i < 2; i++) {
            int idx = tid + i * 256;
            int r = idx >> 2, c = idx & 3;
            const bf16* g = A + (size_t)(row0 + r) * E_DIM + k0 + c * 8;
            __builtin_amdgcn_global_load_lds(
                (const AS1 void*)g, (AS3 void*)(As + idx * 8), 16, 0, 0);
        }
        if constexpr (WB16) {
            const bf16* Wb = (const bf16*)Wp;
#pragma unroll
            for (int i = 0; i < 2; i++) {
                int idx = tid + i * 256;
                int e = idx >> 2, c = idx & 3;
                const bf16* g = Wb + (size_t)(col0 + e) * E_DIM + k0 + c * 8;
                __builtin_amdgcn_global_load_lds(
                    (const AS1 void*)g, (AS3 void*)(Bs + idx * 8), 16, 0, 0);
            }
        } else {
            const float* Wf = (const float*)Wp;
#pragma unroll
            for (int i = 0; i < 2; i++) {
                int idx = tid + i * 256;
                int e = idx >> 2, c = idx & 3;
                const float* wr = Wf + (size_t)(col0 + e) * E_DIM + k0 + c * 8;
                float4 f0 = *(const float4*)wr;
                float4 f1 = *(const float4*)(wr + 4);
                union { bf16 t[8]; uint4 u; } pk;
                pk.t[0] = (bf16)f0.x; pk.t[1] = (bf16)f0.y;
                pk.t[2] = (bf16)f0.z; pk.t[3] = (bf16)f0.w;
                pk.t[4] = (bf16)f1.x; pk.t[5] = (bf16)f1.y;
                pk.t[6] = (bf16)f1.z; pk.t[7] = (bf16)f1.w;
                *(uint4*)(Bs + idx * 8) = pk.u;
            }
        }
        __syncthreads();

        bf16x8 af[4], bfr[4];
#pragma unroll
        for (int t = 0; t < 4; t++) {
            af[t]  = *(const bf16x8*)(As + (wm + t * 16 + l16) * 32 + quad * 8);
            bfr[t] = *(const bf16x8*)(Bs + (wn + t * 16 + l16) * 32 + quad * 8);
        }
#pragma unroll
        for (int mt = 0; mt < 4; mt++)
#pragma unroll
            for (int nt = 0; nt < 4; nt++)
                acc[mt][nt] = __builtin_amdgcn_mfma_f32_16x16x32_bf16(
                    af[mt], bfr[nt], acc[mt][nt], 0, 0, 0);
        __syncthreads();
    }

#pragma unroll
    for (int mt = 0; mt < 4; mt++)
#pragma unroll
        for (int nt = 0; nt < 4; nt++)
#pragma unroll
            for (int rg = 0; rg < 4; rg++) {
                int m = row0 + wm + mt * 16 + quad * 4 + rg;
                int e = col0 + wn + nt * 16 + l16;
                float val = acc[mt][nt][rg];
                if (MODE == 0) {
                    float v2 = (val + bias[e]) * scale;
                    int n = m >> 2, bb = m & 3;
                    int h = e >> 6, d = e & 63;
                    out_bf[((((size_t)bb * H_DIM + h) * N_DIM + n) * D_DIM) + d] = (bf16)v2;
                } else {
                    out_f[(size_t)m * E_DIM + e] = val + bias[e];
                }
            }
}

// ---------------- Chunk stats (unchanged) ----------------
__global__ __launch_bounds__(128) void chunk_stats(
    const bf16* __restrict__ q_s, const bf16* __restrict__ kbuf, const bf16* __restrict__ vbuf,
    const float* __restrict__ mqw, const float* __restrict__ mqb,
    const float* __restrict__ mqg, const float* __restrict__ mqbe,
    const float* __restrict__ mkw, const float* __restrict__ mkb,
    const float* __restrict__ mkg, const float* __restrict__ mkbe,
    float* __restrict__ rf_k_bar, float* __restrict__ rfa_chunk)
{
    int bid = blockIdx.x;
    int c = bid % NC;
    int bh = bid / NC;
    int tid = threadIdx.x;

    __shared__ float qm[64], km[64], qb_s[64], kb_s[64], mu_s[64], sc[128];
    __shared__ float stats[4];

    size_t base = ((size_t)bh * N_DIM + c * 128) * D_DIM;

    if (tid < 64) {
        float s = 0.f;
        for (int p = 0; p < 128; p++) s += (float)q_s[base + p * 64 + tid];
        qm[tid] = s * (1.0f / 128.0f);
    } else {
        int d = tid - 64;
        float s = 0.f;
        for (int p = 0; p < 128; p++) s += (float)kbuf[base + p * 64 + d];
        km[d] = s * (1.0f / 128.0f);
    }
    __syncthreads();

    if (tid < 64) {
        float t = mqb[tid];
        for (int d2 = 0; d2 < 64; d2++) t += qm[d2] * mqw[tid * 64 + d2];
        qb_s[tid] = t;
    } else {
        int d = tid - 64;
        float t = mkb[d];
        for (int d2 = 0; d2 < 64; d2++) t += km[d2] * mkw[d * 64 + d2];
        kb_s[d] = t;
    }
    __syncthreads();

    if (tid == 0) {
        float m = 0.f;
        for (int d = 0; d < 64; d++) m += qb_s[d];
        m *= (1.0f / 64.0f);
        float vv = 0.f;
        for (int d = 0; d < 64; d++) { float x = qb_s[d] - m; vv += x * x; }
        vv *= (1.0f / 64.0f);
        stats[0] = m; stats[1] = rsqrtf(vv + 1e-5f);
    } else if (tid == 64) {
        float m = 0.f;
        for (int d = 0; d < 64; d++) m += kb_s[d];
        m *= (1.0f / 64.0f);
        float vv = 0.f;
        for (int d = 0; d < 64; d++) { float x = kb_s[d] - m; vv += x * x; }
        vv *= (1.0f / 64.0f);
        stats[2] = m; stats[3] = rsqrtf(vv + 1e-5f);
    }
    __syncthreads();

    if (tid < 64) {
        float qn = (qb_s[tid] - stats[0]) * stats[1] * mqg[tid] + mqbe[tid];
        float kn = (kb_s[tid] - stats[2]) * stats[3] * mkg[tid] + mkbe[tid];
        mu_s[tid] = qn + kn;
        rf_k_bar[(size_t)bh * NC * 64 + c * 64 + tid] = kn;
    }
    __syncthreads();

    {
        float dot = 0.f, ss = 0.f;
        const bf16* kr = kbuf + base + tid * 64;
        for (int d = 0; d < 64; d++) {
            float kv = (float)kr[d];
            dot += mu_s[d] * kv;
            ss += kv * kv;
        }
        sc[tid] = dot * 0.125f - 0.125f * 0.5f * ss;
    }
    __syncthreads();
    if (tid == 0) {
        float m = sc[0];
        for (int p = 1; p < 128; p++) m = fmaxf(m, sc[p]);
        stats[0] = m;
    }
    __syncthreads();
    float e = expf(sc[tid] - stats[0]);
    sc[tid] = e;
    __syncthreads();
    if (tid == 0) {
        float s = 0.f;
        for (int p = 0; p < 128; p++) s += sc[p];
        stats[1] = 1.0f / s;
    }
    __syncthreads();
    sc[tid] *= stats[1];
    __syncthreads();

    if (tid < 64) {
        float acc = 0.f;
        for (int p = 0; p < 128; p++) acc += sc[p] * (float)vbuf[base + p * 64 + tid];
        rfa_chunk[(size_t)bh * NC * 64 + c * 64 + tid] = acc;
    }
}

// ---------------- Windowed attention per (b,h,g) — v4 ------------------------
// Round-4-proven staging (padded Ks[288][72]; scalar V-transpose into
// Vt[64][296]) + pinned-layout-only v3 wins:
//   * swapped QK^T: acc[ct] = S^T; lane (l16,q4) holds S[i=l16][j=ct*16+q4*4+rg]
//   * lane-local softmax (row i = l16 fixed per lane; 2 shfl_xor over q4)
//   * PV: O^T = mfma(A = V^T from Vt, B = P^T from the lane's OWN acc regs).
//     The k-slot<->j bijection phi(8*q4+e) = 16*(e>>2) + 4*q4 + (e&3) is
//     absorbed into Vt's column permutation at staging time:
//     col(j) = (j&~31) | ((j>>2)&3)<<3 | ((j>>4)&1)<<2 | (j&3)
//     so the A-fragment is ONE plain b128 read. No P LDS round-trip,
//     no mid-kernel barrier. LDS 79,360 B -> 2 blocks/CU.
__global__ __launch_bounds__(512, 4) void attn_kernel(
    const bf16* __restrict__ qin, const bf16* __restrict__ kbuf, const bf16* __restrict__ vbuf,
    const float* __restrict__ rf_k_bar, const float* __restrict__ rfa_chunk,
    bf16* __restrict__ aout)
{
    int bid = blockIdx.x;
    int g = bid & (G_WIN - 1);
    int bh = bid / G_WIN;          // b*H + h
    int b = bh >> 4, h = bh & 15;
    int tid = threadIdx.x;
    int lane = tid & 63;
    int wv = tid >> 6;             // 0..7
    int q4 = lane >> 4;            // 0..3
    int l16 = lane & 15;

    __shared__ __align__(16) short Ks[288 * 72];   // 41,472 B (pad 72 -> 2-way banks)
    __shared__ __align__(16) short Vt[64 * 296];   // 37,888 B (V^T, phi-permuted cols)

    size_t kvbase = (size_t)bh * N_DIM * D_DIM;
    int k0g = g * 128 - 128;       // global key index of local j=0

    // ---- stage K local: 256 keys x 64 d (identical to round 4) ----
#pragma unroll
    for (int i = 0; i < 4; i++) {
        int ci = tid + i * 512;            // 0..2047
        int key = ci >> 3, chc = ci & 7;
        int kidx = k0g + key; if (kidx < 0) kidx = 0;   // masked later
        bf16x8 v = *(const bf16x8*)(kbuf + kvbase + (size_t)kidx * 64 + chc * 8);
        *(bf16x8*)(Ks + key * 72 + chc * 8) = v;
    }
    // ---- stage rf_k_bar (fp32 32x64) -> Ks rows 256..287 (identical) ----
    if (tid < 256) {
        int c = tid >> 3, chc = tid & 7;
        const float* src = rf_k_bar + (size_t)bh * NC * 64 + c * 64 + chc * 8;
        float4 f0 = *(const float4*)src;
        float4 f1 = *(const float4*)(src + 4);
        union { bf16 t[8]; bf16x8 v; } pk;
        pk.t[0] = (bf16)f0.x; pk.t[1] = (bf16)f0.y;
        pk.t[2] = (bf16)f0.z; pk.t[3] = (bf16)f0.w;
        pk.t[4] = (bf16)f1.x; pk.t[5] = (bf16)f1.y;
        pk.t[6] = (bf16)f1.z; pk.t[7] = (bf16)f1.w;
        *(bf16x8*)(Ks + (256 + c) * 72 + chc * 8) = pk.v;
    }
    // ---- stage V transposed: Vt[d][col(key)] (phi-permuted columns) ----
#pragma unroll
    for (int i = 0; i < 4; i++) {
        int ci = tid + i * 512;            // 0..2047
        int key = ci & 255, dc = ci >> 8;  // dc 0..7
        int kidx = k0g + key; if (kidx < 0) kidx = 0;
        union { bf16x8 v; short s[8]; } u;
        u.v = *(const bf16x8*)(vbuf + kvbase + (size_t)kidx * 64 + dc * 8);
        int colp = (key & ~31) | (((key >> 2) & 3) << 3)
                 | (((key >> 4) & 1) << 2) | (key & 3);
#pragma unroll
        for (int jj = 0; jj < 8; jj++)
            Vt[(dc * 8 + jj) * 296 + colp] = u.s[jj];
    }
    // ---- stage rfa_chunk^T -> Vt cols 256..287 (phi-permuted) ----
    if (tid < 256) {
        int d = tid >> 2, cg = tid & 3;
        const float* rc = rfa_chunk + (size_t)bh * NC * 64;
#pragma unroll
        for (int jj = 0; jj < 8; jj++) {
            int c = cg * 8 + jj;
            int p = (((c >> 2) & 3) << 3) | (((c >> 4) & 1) << 2) | (c & 3);
            union { bf16 bv; short s; } cv;
            cv.bv = (bf16)rc[(size_t)c * 64 + d];
            Vt[d * 296 + 256 + p] = cv.s;
        }
    }

    // ---- Q fragments (global): B-operand rows i = l16 of this wave ----
    bf16x8 bq0, bq1;
    {
        const bf16* qrow = qin + kvbase + (size_t)(g * 128 + wv * 16 + l16) * 64 + q4 * 8;
        bq0 = *(const bf16x8*)qrow;
        bq1 = *(const bf16x8*)(qrow + 32);
    }

    __syncthreads();

    // ---- QK^T swapped: A = K rows (ct*16+l16), B = Q rows (i = l16) ----
    f32x4 acc[18] = {};
#pragma unroll
    for (int ct = 0; ct < 18; ct++) {
        int r = ct * 16 + l16;
        bf16x8 ak0 = *(const bf16x8*)(Ks + r * 72 + q4 * 8);
        bf16x8 ak1 = *(const bf16x8*)(Ks + r * 72 + 32 + q4 * 8);
        acc[ct] = __builtin_amdgcn_mfma_f32_16x16x32_bf16(ak0, bq0, acc[ct], 0, 0, 0);
        acc[ct] = __builtin_amdgcn_mfma_f32_16x16x32_bf16(ak1, bq1, acc[ct], 0, 0, 0);
    }

    // ---- mask + lane-local row max (row i = l16 fixed per lane) ----
    int qi = wv * 16 + l16;            // query row within window
    float m = -1e30f;
#pragma unroll
    for (int ct = 0; ct < 18; ct++) {
        int jbase = ct * 16 + q4 * 4;
#pragma unroll
        for (int rg = 0; rg < 4; rg++) {
            int j = jbase + rg;
            bool ok = (j < 256) ? (k0g + j >= 0 && j <= qi + 128) : ((j - 256) < g);
            float s = ok ? acc[ct][rg] : -1e9f;
            acc[ct][rg] = s;
            m = fmaxf(m, s);
        }
    }
    m = fmaxf(m, __shfl_xor(m, 16));
    m = fmaxf(m, __shfl_xor(m, 32));

    // ---- exp + row sum (normalization deferred to epilogue) ----
    float sum = 0.f;
#pragma unroll
    for (int ct = 0; ct < 18; ct++)
#pragma unroll
        for (int rg = 0; rg < 4; rg++) {
            float p = __expf(acc[ct][rg] - m);
            acc[ct][rg] = p;
            sum += p;
        }
    sum += __shfl_xor(sum, 16);
    sum += __shfl_xor(sum, 32);
    float rinv = 1.0f / sum;

    // ---- P·V: A = V^T (one b128 read, phi-permuted cols), B = P^T from regs --
    f32x4 accO[4] = {};
#pragma unroll
    for (int cc = 0; cc < 9; cc++) {
        union { bf16 t[8]; bf16x8 v; } pb;
#pragma unroll
        for (int e = 0; e < 4; e++) {
            pb.t[e]     = (bf16)acc[2 * cc][e];
            pb.t[4 + e] = (bf16)acc[2 * cc + 1][e];
        }
#pragma unroll
        for (int dt = 0; dt < 4; dt++) {
            bf16x8 av = *(const bf16x8*)(Vt + (dt * 16 + l16) * 296 + (cc * 4 + q4) * 8);
            accO[dt] = __builtin_amdgcn_mfma_f32_16x16x32_bf16(av, pb.v, accO[dt], 0, 0, 0);
        }
    }

    // ---- epilogue: O^T[d][i]; lane has 4 consecutive d per dt; 8B stores ----
    int nn = g * 128 + wv * 16 + l16;
    size_t obase = ((size_t)nn * B_DIM + b) * E_DIM + h * 64;
#pragma unroll
    for (int dt = 0; dt < 4; dt++) {
        union { bf16 t[4]; uint2 u; } o;
#pragma unroll
        for (int rg = 0; rg < 4; rg++) o.t[rg] = (bf16)(accO[dt][rg] * rinv);
        *(uint2*)(aout + obase + dt * 16 + q4 * 4) = o.u;
    }
}

extern "C" void kernel_launch(void* const* d_in, const int* in_sizes, int n_in,
                              void* d_out, int out_size, void* d_ws, size_t ws_size,
                              hipStream_t stream) {
    const float* query = (const float*)d_in[0];
    const float* Wq   = (const float*)d_in[1];
    const float* bq   = (const float*)d_in[2];
    const float* Wk   = (const float*)d_in[3];
    const float* bk   = (const float*)d_in[4];
    const float* Wv   = (const float*)d_in[5];
    const float* bv   = (const float*)d_in[6];
    const float* Wo   = (const float*)d_in[7];
    const float* bo   = (const float*)d_in[8];
    const float* mqw  = (const float*)d_in[9];
    const float* mqb  = (const float*)d_in[10];
    const float* mqg  = (const float*)d_in[11];
    const float* mqbe = (const float*)d_in[12];
    const float* mkw  = (const float*)d_in[13];
    const float* mkb  = (const float*)d_in[14];
    const float* mkg  = (const float*)d_in[15];
    const float* mkbe = (const float*)d_in[16];

    const size_t SZ = (size_t)B_DIM * H_DIM * N_DIM * D_DIM; // 16,777,216 elems
    const size_t STATS = (size_t)B_DIM * H_DIM * NC * D_DIM; // 131,072 elems

    bf16* kb = (bf16*)d_ws;
    bf16* vb = kb + SZ;
    float* rf_k_bar  = (float*)(vb + SZ);
    float* rfa_chunk = rf_k_bar + STATS;

    size_t base_bytes = 2 * SZ * sizeof(bf16) + 2 * STATS * sizeof(float);
    size_t wmat = (size_t)E_DIM * E_DIM;
    bool wb16   = ws_size >= base_bytes + 4 * wmat * sizeof(bf16);
    bool big_ws = ws_size >= base_bytes + 4 * wmat * sizeof(bf16) + SZ * sizeof(bf16);
    bf16* wq_b = (bf16*)((char*)d_ws + base_bytes);
    bf16* wk_b = wq_b + wmat;
    bf16* wv_b = wk_b + wmat;
    bf16* wo_b = wv_b + wmat;
    bf16* att_ws = wo_b + wmat;

    float* outf = (float*)d_out;
    bf16* qb  = (bf16*)d_out;      // 32 MiB
    bf16* qbf = qb + SZ;           // 32 MiB

    dim3 gblk(256);
    int ggrd = (E_DIM / 128) * (M_ROWS / 128);   // 1024 blocks

    cvt_f32_bf16<<<(M_ROWS * E_DIM) / (256 * 8), 256, 0, stream>>>(query, qbf);
    if (wb16) {
        int wblk = (int)(wmat / (256 * 8));
        cvt_f32_bf16<<<wblk, 256, 0, stream>>>(Wq, wq_b);
        cvt_f32_bf16<<<wblk, 256, 0, stream>>>(Wk, wk_b);
        cvt_f32_bf16<<<wblk, 256, 0, stream>>>(Wv, wv_b);
        cvt_f32_bf16<<<wblk, 256, 0, stream>>>(Wo, wo_b);
    }

    if (wb16) {
        gemm_mfma<0, true><<<ggrd, gblk, 0, stream>>>(qbf, wq_b, bq, 0.125f, qb, nullptr);
        gemm_mfma<0, true><<<ggrd, gblk, 0, stream>>>(qbf, wk_b, bk, 1.0f, kb, nullptr);
        gemm_mfma<0, true><<<ggrd, gblk, 0, stream>>>(qbf, wv_b, bv, 1.0f, vb, nullptr);
    } else {
        gemm_mfma<0, false><<<ggrd, gblk, 0, stream>>>(qbf, Wq, bq, 0.125f, qb, nullptr);
        gemm_mfma<0, false><<<ggrd, gblk, 0, stream>>>(qbf, Wk, bk, 1.0f, kb, nullptr);
        gemm_mfma<0, false><<<ggrd, gblk, 0, stream>>>(qbf, Wv, bv, 1.0f, vb, nullptr);
    }

    chunk_stats<<<B_DIM * H_DIM * NC, 128, 0, stream>>>(
        qb, kb, vb, mqw, mqb, mqg, mqbe, mkw, mkb, mkg, mkbe, rf_k_bar, rfa_chunk);

    bf16* attn_dst = big_ws ? att_ws : qbf;
    attn_kernel<<<B_DIM * H_DIM * G_WIN, 512, 0, stream>>>(
        qb, kb, vb, rf_k_bar, rfa_chunk, attn_dst);

    const bf16* gemm_in;
    if (big_ws) {
        gemm_in = att_ws;
    } else {
        (void)hipMemcpyAsync(kb, qbf, SZ * sizeof(bf16), hipMemcpyDeviceToDevice, stream);
        gemm_in = kb;
    }

    if (wb16) {
        gemm_mfma<1, true><<<ggrd, gblk, 0, stream>>>(gemm_in, wo_b, bo, 1.0f, nullptr, outf);
    } else {
        gemm_mfma<1, false><<<ggrd, gblk, 0, stream>>>(gemm_in, Wo, bo, 1.0f, nullptr, outf);
    }
}

// Round 7
// 402.988 us; speedup vs baseline: 10.8866x; 1.0523x over previous
//
#include <hip/hip_runtime.h>
#include <hip/hip_bf16.h>

typedef __hip_bfloat16 bf16;
typedef __attribute__((ext_vector_type(8))) short bf16x8;
typedef __attribute__((ext_vector_type(4))) float f32x4;

#define E_DIM 1024
#define H_DIM 16
#define N_DIM 4096
#define B_DIM 4
#define D_DIM 64
#define G_WIN 32   // N / 128
#define NC 32      // N / 128
#define M_ROWS 16384  // N*B

#define AS1 __attribute__((address_space(1)))
#define AS3 __attribute__((address_space(3)))

// ---------------- fp32 -> bf16 bulk convert (8 elems/thread) ----------------
__global__ __launch_bounds__(256) void cvt_f32_bf16(
    const float* __restrict__ in, bf16* __restrict__ out)
{
    int i = (blockIdx.x * 256 + threadIdx.x) * 8;
    float4 f0 = *(const float4*)(in + i);
    float4 f1 = *(const float4*)(in + i + 4);
    union { bf16 t[8]; uint4 u; } pk;
    pk.t[0] = (bf16)f0.x; pk.t[1] = (bf16)f0.y; pk.t[2] = (bf16)f0.z; pk.t[3] = (bf16)f0.w;
    pk.t[4] = (bf16)f1.x; pk.t[5] = (bf16)f1.y; pk.t[6] = (bf16)f1.z; pk.t[7] = (bf16)f1.w;
    *(uint4*)(out + i) = pk.u;
}

// ---------------- MFMA GEMM ----------------
// out[m,e] = sum_k A[m,k] * W[e,k]  (A bf16 row-major [M][K])
// 128x128 tile, 4 waves of 64x64, mfma_f32_16x16x32_bf16, BK=32.
// Block mapping: chunk = bid&7 (XCD), lc = bid>>3; colt = lc>>4, rowsub = lc&15;
// row0 = (chunk*16+rowsub)*128  -> each XCD owns 16 row-panels (4MB A, L2-fit)
// and iterates cols slowly (W panel reused 16x consecutively).
// MODE 0: (val + bias)*scale -> bf16 scatter [B,H,N,D]
// MODE 1: val + bias -> fp32 row-major [M][E]
// MODE 2: fused QKV; N=3072 stacked W/bias; per-block output select:
//         sel = col0>>10 -> {out_bf(q, *scale), out_k, out_v}; e_local = e&1023.
template<int MODE, bool WB16>
__global__ __launch_bounds__(256) void gemm_mfma(
    const bf16* __restrict__ A, const void* __restrict__ Wp,
    const float* __restrict__ bias, float scale,
    bf16* __restrict__ out_bf, float* __restrict__ out_f,
    bf16* __restrict__ out_k, bf16* __restrict__ out_v)
{
    __shared__ bf16 As[128 * 32];
    __shared__ bf16 Bs[128 * 32];
    int tid  = threadIdx.x;
    int lane = tid & 63;
    int wv   = tid >> 6;
    int wm   = (wv >> 1) * 64;
    int wn   = (wv & 1) * 64;
    int quad = lane >> 4;
    int l16  = lane & 15;

    int chunk  = blockIdx.x & 7;
    int lc     = blockIdx.x >> 3;
    int colt   = lc >> 4;
    int rowsub = lc & 15;
    int col0 = colt * 128;
    int row0 = (chunk * 16 + rowsub) * 128;

    f32x4 acc[4][4] = {};

    for (int k0 = 0; k0 < E_DIM; k0 += 32) {
#pragma unroll
        for (int i = 0; i < 2; i++) {
            int idx = tid + i * 256;
            int r = idx >> 2, c = idx & 3;
            const bf16* g = A + (size_t)(row0 + r) * E_DIM + k0 + c * 8;
            __builtin_amdgcn_global_load_lds(
                (const AS1 void*)g, (AS3 void*)(As + idx * 8), 16, 0, 0);
        }
        if constexpr (WB16) {
            const bf16* Wb = (const bf16*)Wp;
#pragma unroll
            for (int i = 0; i < 2; i++) {
                int idx = tid + i * 256;
                int e = idx >> 2, c = idx & 3;
                const bf16* g = Wb + (size_t)(col0 + e) * E_DIM + k0 + c * 8;
                __builtin_amdgcn_global_load_lds(
                    (const AS1 void*)g, (AS3 void*)(Bs + idx * 8), 16, 0, 0);
            }
        } else {
            const float* Wf = (const float*)Wp;
#pragma unroll
            for (int i = 0; i < 2; i++) {
                int idx = tid + i * 256;
                int e = idx >> 2, c = idx & 3;
                const float* wr = Wf + (size_t)(col0 + e) * E_DIM + k0 + c * 8;
                float4 f0 = *(const float4*)wr;
                float4 f1 = *(const float4*)(wr + 4);
                union { bf16 t[8]; uint4 u; } pk;
                pk.t[0] = (bf16)f0.x; pk.t[1] = (bf16)f0.y;
                pk.t[2] = (bf16)f0.z; pk.t[3] = (bf16)f0.w;
                pk.t[4] = (bf16)f1.x; pk.t[5] = (bf16)f1.y;
                pk.t[6] = (bf16)f1.z; pk.t[7] = (bf16)f1.w;
                *(uint4*)(Bs + idx * 8) = pk.u;
            }
        }
        __syncthreads();

        bf16x8 af[4], bfr[4];
#pragma unroll
        for (int t = 0; t < 4; t++) {
            af[t]  = *(const bf16x8*)(As + (wm + t * 16 + l16) * 32 + quad * 8);
            bfr[t] = *(const bf16x8*)(Bs + (wn + t * 16 + l16) * 32 + quad * 8);
        }
#pragma unroll
        for (int mt = 0; mt < 4; mt++)
#pragma unroll
            for (int nt = 0; nt < 4; nt++)
                acc[mt][nt] = __builtin_amdgcn_mfma_f32_16x16x32_bf16(
                    af[mt], bfr[nt], acc[mt][nt], 0, 0, 0);
        __syncthreads();
    }

    // output select (block-uniform for MODE 2)
    bf16* dst = out_bf;
    float scl = scale;
    if (MODE == 2) {
        int sel = col0 >> 10;
        dst = (sel == 0) ? out_bf : ((sel == 1) ? out_k : out_v);
        scl = (sel == 0) ? scale : 1.0f;
    }

#pragma unroll
    for (int mt = 0; mt < 4; mt++)
#pragma unroll
        for (int nt = 0; nt < 4; nt++)
#pragma unroll
            for (int rg = 0; rg < 4; rg++) {
                int m = row0 + wm + mt * 16 + quad * 4 + rg;
                int e = col0 + wn + nt * 16 + l16;
                float val = acc[mt][nt][rg];
                if (MODE == 1) {
                    out_f[(size_t)m * E_DIM + e] = val + bias[e];
                } else {
                    float v2 = (val + bias[e]) * scl;
                    int el = e & 1023;
                    int n = m >> 2, bb = m & 3;
                    int h = el >> 6, d = el & 63;
                    dst[((((size_t)bb * H_DIM + h) * N_DIM + n) * D_DIM) + d] = (bf16)v2;
                }
            }
}

// ---------------- Chunk stats (wave-parallel reductions) ----------------
__global__ __launch_bounds__(128) void chunk_stats(
    const bf16* __restrict__ q_s, const bf16* __restrict__ kbuf, const bf16* __restrict__ vbuf,
    const float* __restrict__ mqw, const float* __restrict__ mqb,
    const float* __restrict__ mqg, const float* __restrict__ mqbe,
    const float* __restrict__ mkw, const float* __restrict__ mkb,
    const float* __restrict__ mkg, const float* __restrict__ mkbe,
    float* __restrict__ rf_k_bar, float* __restrict__ rfa_chunk)
{
    int bid = blockIdx.x;
    int c = bid % NC;
    int bh = bid / NC;
    int tid = threadIdx.x;
    int lane = tid & 63;
    int wid = tid >> 6;

    __shared__ float qm[64], km[64], mu_s[64], sc[128];
    __shared__ float parts[4];

    size_t base = ((size_t)bh * N_DIM + c * 128) * D_DIM;

    // per-chunk means (wave0 -> q, wave1 -> k); lanes = d, coalesced loads
    if (tid < 64) {
        float s = 0.f;
        for (int p = 0; p < 128; p++) s += (float)q_s[base + p * 64 + tid];
        qm[tid] = s * (1.0f / 128.0f);
    } else {
        int d = tid - 64;
        float s = 0.f;
        for (int p = 0; p < 128; p++) s += (float)kbuf[base + p * 64 + d];
        km[d] = s * (1.0f / 128.0f);
    }
    __syncthreads();

    // matvec + layernorm, reductions via shfl within each 64-lane wave
    {
        float t;
        if (wid == 0) {
            t = mqb[lane];
            for (int d2 = 0; d2 < 64; d2++) t += qm[d2] * mqw[lane * 64 + d2];
        } else {
            t = mkb[lane];
            for (int d2 = 0; d2 < 64; d2++) t += km[d2] * mkw[lane * 64 + d2];
        }
        float s = t;
        s += __shfl_xor(s, 1);  s += __shfl_xor(s, 2);  s += __shfl_xor(s, 4);
        s += __shfl_xor(s, 8);  s += __shfl_xor(s, 16); s += __shfl_xor(s, 32);
        float mean = s * (1.0f / 64.0f);
        float x = t - mean;
        float v2 = x * x;
        v2 += __shfl_xor(v2, 1);  v2 += __shfl_xor(v2, 2);  v2 += __shfl_xor(v2, 4);
        v2 += __shfl_xor(v2, 8);  v2 += __shfl_xor(v2, 16); v2 += __shfl_xor(v2, 32);
        float rstd = rsqrtf(v2 * (1.0f / 64.0f) + 1e-5f);
        if (wid == 0) {
            qm[lane] = x * rstd * mqg[lane] + mqbe[lane];       // qn
        } else {
            float kn = x * rstd * mkg[lane] + mkbe[lane];
            km[lane] = kn;
            rf_k_bar[(size_t)bh * NC * 64 + c * 64 + lane] = kn;
        }
    }
    __syncthreads();
    if (tid < 64) mu_s[tid] = qm[tid] + km[tid];
    __syncthreads();

    // per-key logit
    float scv;
    {
        float dot = 0.f, ss = 0.f;
        const bf16* kr = kbuf + base + tid * 64;
        for (int d = 0; d < 64; d++) {
            float kv = (float)kr[d];
            dot += mu_s[d] * kv;
            ss += kv * kv;
        }
        scv = dot * 0.125f - 0.0625f * ss;
    }
    // softmax over 128 (2 waves): shfl-reduce + cross-wave combine
    {
        float mv = scv;
        mv = fmaxf(mv, __shfl_xor(mv, 1));  mv = fmaxf(mv, __shfl_xor(mv, 2));
        mv = fmaxf(mv, __shfl_xor(mv, 4));  mv = fmaxf(mv, __shfl_xor(mv, 8));
        mv = fmaxf(mv, __shfl_xor(mv, 16)); mv = fmaxf(mv, __shfl_xor(mv, 32));
        if (lane == 0) parts[wid] = mv;
        __syncthreads();
        float mall = fmaxf(parts[0], parts[1]);
        float e = expf(scv - mall);
        float sv = e;
        sv += __shfl_xor(sv, 1);  sv += __shfl_xor(sv, 2);  sv += __shfl_xor(sv, 4);
        sv += __shfl_xor(sv, 8);  sv += __shfl_xor(sv, 16); sv += __shfl_xor(sv, 32);
        if (lane == 0) parts[2 + wid] = sv;
        __syncthreads();
        float inv = 1.0f / (parts[2] + parts[3]);
        sc[tid] = e * inv;
    }
    __syncthreads();

    if (tid < 64) {
        float acc = 0.f;
        for (int p = 0; p < 128; p++) acc += sc[p] * (float)vbuf[base + p * 64 + tid];
        rfa_chunk[(size_t)bh * NC * 64 + c * 64 + tid] = acc;
    }
}

// ---------------- Windowed attention per (b,h,g) — v5 ------------------------
// = v4 + exact causal tile-skip (wave-uniform) + s_setprio around MFMA.
// Tile ct (j in [16ct,16ct+16)) is fully masked for wave wv iff ct >= wv+9
// (causal), or g==0 && ct<8 (left edge), ct==16 && g==0, ct==17 && g<=16.
// Skipped tiles keep acc == 0 -> P == 0 exactly (skip mask/exp too).
__global__ __launch_bounds__(512, 4) void attn_kernel(
    const bf16* __restrict__ qin, const bf16* __restrict__ kbuf, const bf16* __restrict__ vbuf,
    const float* __restrict__ rf_k_bar, const float* __restrict__ rfa_chunk,
    bf16* __restrict__ aout)
{
    int bid = blockIdx.x;
    int g = bid & (G_WIN - 1);
    int bh = bid / G_WIN;          // b*H + h
    int b = bh >> 4, h = bh & 15;
    int tid = threadIdx.x;
    int lane = tid & 63;
    int wv = tid >> 6;             // 0..7
    int q4 = lane >> 4;            // 0..3
    int l16 = lane & 15;

    __shared__ __align__(16) short Ks[288 * 72];   // 41,472 B (pad 72)
    __shared__ __align__(16) short Vt[64 * 296];   // 37,888 B (V^T, phi-permuted)

    size_t kvbase = (size_t)bh * N_DIM * D_DIM;
    int k0g = g * 128 - 128;

    // ---- stage K local ----
#pragma unroll
    for (int i = 0; i < 4; i++) {
        int ci = tid + i * 512;
        int key = ci >> 3, chc = ci & 7;
        int kidx = k0g + key; if (kidx < 0) kidx = 0;
        bf16x8 v = *(const bf16x8*)(kbuf + kvbase + (size_t)kidx * 64 + chc * 8);
        *(bf16x8*)(Ks + key * 72 + chc * 8) = v;
    }
    // ---- rf_k_bar -> Ks rows 256..287 ----
    if (tid < 256) {
        int c = tid >> 3, chc = tid & 7;
        const float* src = rf_k_bar + (size_t)bh * NC * 64 + c * 64 + chc * 8;
        float4 f0 = *(const float4*)src;
        float4 f1 = *(const float4*)(src + 4);
        union { bf16 t[8]; bf16x8 v; } pk;
        pk.t[0] = (bf16)f0.x; pk.t[1] = (bf16)f0.y;
        pk.t[2] = (bf16)f0.z; pk.t[3] = (bf16)f0.w;
        pk.t[4] = (bf16)f1.x; pk.t[5] = (bf16)f1.y;
        pk.t[6] = (bf16)f1.z; pk.t[7] = (bf16)f1.w;
        *(bf16x8*)(Ks + (256 + c) * 72 + chc * 8) = pk.v;
    }
    // ---- V transposed, phi-permuted cols ----
#pragma unroll
    for (int i = 0; i < 4; i++) {
        int ci = tid + i * 512;
        int key = ci & 255, dc = ci >> 8;
        int kidx = k0g + key; if (kidx < 0) kidx = 0;
        union { bf16x8 v; short s[8]; } u;
        u.v = *(const bf16x8*)(vbuf + kvbase + (size_t)kidx * 64 + dc * 8);
        int colp = (key & ~31) | (((key >> 2) & 3) << 3)
                 | (((key >> 4) & 1) << 2) | (key & 3);
#pragma unroll
        for (int jj = 0; jj < 8; jj++)
            Vt[(dc * 8 + jj) * 296 + colp] = u.s[jj];
    }
    // ---- rfa_chunk^T -> Vt cols 256..287 ----
    if (tid < 256) {
        int d = tid >> 2, cg = tid & 3;
        const float* rc = rfa_chunk + (size_t)bh * NC * 64;
#pragma unroll
        for (int jj = 0; jj < 8; jj++) {
            int c = cg * 8 + jj;
            int p = (((c >> 2) & 3) << 3) | (((c >> 4) & 1) << 2) | (c & 3);
            union { bf16 bv; short s; } cv;
            cv.bv = (bf16)rc[(size_t)c * 64 + d];
            Vt[d * 296 + 256 + p] = cv.s;
        }
    }

    bf16x8 bq0, bq1;
    {
        const bf16* qrow = qin + kvbase + (size_t)(g * 128 + wv * 16 + l16) * 64 + q4 * 8;
        bq0 = *(const bf16x8*)qrow;
        bq1 = *(const bf16x8*)(qrow + 32);
    }

    __syncthreads();

    // ---- QK^T swapped (tile-skip) ----
    f32x4 acc[18] = {};
    __builtin_amdgcn_s_setprio(1);
#pragma unroll
    for (int ct = 0; ct < 18; ct++) {
        bool live = (ct < 16) ? (ct <= wv + 8 && !(g == 0 && ct < 8))
                              : ((ct == 16) ? (g > 0) : (g > 16));
        if (!live) continue;
        int r = ct * 16 + l16;
        bf16x8 ak0 = *(const bf16x8*)(Ks + r * 72 + q4 * 8);
        bf16x8 ak1 = *(const bf16x8*)(Ks + r * 72 + 32 + q4 * 8);
        acc[ct] = __builtin_amdgcn_mfma_f32_16x16x32_bf16(ak0, bq0, acc[ct], 0, 0, 0);
        acc[ct] = __builtin_amdgcn_mfma_f32_16x16x32_bf16(ak1, bq1, acc[ct], 0, 0, 0);
    }
    __builtin_amdgcn_s_setprio(0);

    // ---- mask + lane-local row max (skip dead tiles; acc stays 0 -> P=0) ----
    int qi = wv * 16 + l16;
    float m = -1e30f;
#pragma unroll
    for (int ct = 0; ct < 18; ct++) {
        bool live = (ct < 16) ? (ct <= wv + 8 && !(g == 0 && ct < 8))
                              : ((ct == 16) ? (g > 0) : (g > 16));
        if (!live) continue;
        int jbase = ct * 16 + q4 * 4;
#pragma unroll
        for (int rg = 0; rg < 4; rg++) {
            int j = jbase + rg;
            bool ok = (j < 256) ? (k0g + j >= 0 && j <= qi + 128) : ((j - 256) < g);
            float s = ok ? acc[ct][rg] : -1e9f;
            acc[ct][rg] = s;
            m = fmaxf(m, s);
        }
    }
    m = fmaxf(m, __shfl_xor(m, 16));
    m = fmaxf(m, __shfl_xor(m, 32));

    // ---- exp + row sum (live tiles only; dead tiles contribute exactly 0) ----
    float sum = 0.f;
#pragma unroll
    for (int ct = 0; ct < 18; ct++) {
        bool live = (ct < 16) ? (ct <= wv + 8 && !(g == 0 && ct < 8))
                              : ((ct == 16) ? (g > 0) : (g > 16));
        if (!live) continue;
#pragma unroll
        for (int rg = 0; rg < 4; rg++) {
            float p = __expf(acc[ct][rg] - m);
            acc[ct][rg] = p;
            sum += p;
        }
    }
    sum += __shfl_xor(sum, 16);
    sum += __shfl_xor(sum, 32);
    float rinv = 1.0f / sum;

    // ---- P·V (cc-skip when both tiles dead) ----
    f32x4 accO[4] = {};
    __builtin_amdgcn_s_setprio(1);
#pragma unroll
    for (int cc = 0; cc < 9; cc++) {
        bool live = (cc < 8) ? (2 * cc <= wv + 8 && !(g == 0 && cc < 4)) : (g > 0);
        if (!live) continue;
        union { bf16 t[8]; bf16x8 v; } pb;
#pragma unroll
        for (int e = 0; e < 4; e++) {
            pb.t[e]     = (bf16)acc[2 * cc][e];
            pb.t[4 + e] = (bf16)acc[2 * cc + 1][e];
        }
#pragma unroll
        for (int dt = 0; dt < 4; dt++) {
            bf16x8 av = *(const bf16x8*)(Vt + (dt * 16 + l16) * 296 + (cc * 4 + q4) * 8);
            accO[dt] = __builtin_amdgcn_mfma_f32_16x16x32_bf16(av, pb.v, accO[dt], 0, 0, 0);
        }
    }
    __builtin_amdgcn_s_setprio(0);

    // ---- epilogue ----
    int nn = g * 128 + wv * 16 + l16;
    size_t obase = ((size_t)nn * B_DIM + b) * E_DIM + h * 64;
#pragma unroll
    for (int dt = 0; dt < 4; dt++) {
        union { bf16 t[4]; uint2 u; } o;
#pragma unroll
        for (int rg = 0; rg < 4; rg++) o.t[rg] = (bf16)(accO[dt][rg] * rinv);
        *(uint2*)(aout + obase + dt * 16 + q4 * 4) = o.u;
    }
}

extern "C" void kernel_launch(void* const* d_in, const int* in_sizes, int n_in,
                              void* d_out, int out_size, void* d_ws, size_t ws_size,
                              hipStream_t stream) {
    const float* query = (const float*)d_in[0];
    const float* Wq   = (const float*)d_in[1];
    const float* bq   = (const float*)d_in[2];
    const float* Wk   = (const float*)d_in[3];
    const float* bk   = (const float*)d_in[4];
    const float* Wv   = (const float*)d_in[5];
    const float* bv   = (const float*)d_in[6];
    const float* Wo   = (const float*)d_in[7];
    const float* bo   = (const float*)d_in[8];
    const float* mqw  = (const float*)d_in[9];
    const float* mqb  = (const float*)d_in[10];
    const float* mqg  = (const float*)d_in[11];
    const float* mqbe = (const float*)d_in[12];
    const float* mkw  = (const float*)d_in[13];
    const float* mkb  = (const float*)d_in[14];
    const float* mkg  = (const float*)d_in[15];
    const float* mkbe = (const float*)d_in[16];

    const size_t SZ = (size_t)B_DIM * H_DIM * N_DIM * D_DIM; // 16,777,216 elems
    const size_t STATS = (size_t)B_DIM * H_DIM * NC * D_DIM; // 131,072 elems

    bf16* kb = (bf16*)d_ws;
    bf16* vb = kb + SZ;
    float* rf_k_bar  = (float*)(vb + SZ);
    float* rfa_chunk = rf_k_bar + STATS;

    size_t base_bytes = 2 * SZ * sizeof(bf16) + 2 * STATS * sizeof(float);
    size_t wmat = (size_t)E_DIM * E_DIM;
    size_t wb16_bytes = base_bytes + 4 * wmat * sizeof(bf16) + 3072 * sizeof(float);
    bool wb16   = ws_size >= wb16_bytes;
    bool big_ws = ws_size >= wb16_bytes + SZ * sizeof(bf16);
    bf16* wq_b = (bf16*)((char*)d_ws + base_bytes);
    bf16* wk_b = wq_b + wmat;
    bf16* wv_b = wk_b + wmat;
    bf16* wo_b = wv_b + wmat;
    float* biasQKV = (float*)(wo_b + wmat);          // 3072 floats
    bf16* att_ws = (bf16*)(biasQKV + 3072);

    float* outf = (float*)d_out;
    bf16* qb  = (bf16*)d_out;      // 32 MiB
    bf16* qbf = qb + SZ;           // 32 MiB

    dim3 gblk(256);
    int ggrd1 = (E_DIM / 128) * (M_ROWS / 128);      // 1024 blocks (single GEMM)
    int ggrd3 = 3 * ggrd1;                           // 3072 blocks (fused QKV)

    // 1. query fp32 -> bf16 (and weights + stacked bias, if workspace allows)
    cvt_f32_bf16<<<(M_ROWS * E_DIM) / (256 * 8), 256, 0, stream>>>(query, qbf);
    if (wb16) {
        int wblk = (int)(wmat / (256 * 8));
        cvt_f32_bf16<<<wblk, 256, 0, stream>>>(Wq, wq_b);
        cvt_f32_bf16<<<wblk, 256, 0, stream>>>(Wk, wk_b);
        cvt_f32_bf16<<<wblk, 256, 0, stream>>>(Wv, wv_b);
        cvt_f32_bf16<<<wblk, 256, 0, stream>>>(Wo, wo_b);
        (void)hipMemcpyAsync(biasQKV,        bq, 1024 * sizeof(float), hipMemcpyDeviceToDevice, stream);
        (void)hipMemcpyAsync(biasQKV + 1024, bk, 1024 * sizeof(float), hipMemcpyDeviceToDevice, stream);
        (void)hipMemcpyAsync(biasQKV + 2048, bv, 1024 * sizeof(float), hipMemcpyDeviceToDevice, stream);
    }

    // 2. projections
    if (wb16) {
        gemm_mfma<2, true><<<ggrd3, gblk, 0, stream>>>(
            qbf, wq_b, biasQKV, 0.125f, qb, nullptr, kb, vb);
    } else {
        gemm_mfma<0, false><<<ggrd1, gblk, 0, stream>>>(qbf, Wq, bq, 0.125f, qb, nullptr, nullptr, nullptr);
        gemm_mfma<0, false><<<ggrd1, gblk, 0, stream>>>(qbf, Wk, bk, 1.0f, kb, nullptr, nullptr, nullptr);
        gemm_mfma<0, false><<<ggrd1, gblk, 0, stream>>>(qbf, Wv, bv, 1.0f, vb, nullptr, nullptr, nullptr);
    }

    // 3. chunk stats
    chunk_stats<<<B_DIM * H_DIM * NC, 128, 0, stream>>>(
        qb, kb, vb, mqw, mqb, mqg, mqbe, mkw, mkb, mkg, mkbe, rf_k_bar, rfa_chunk);

    // 4. attention
    bf16* attn_dst = big_ws ? att_ws : qbf;
    attn_kernel<<<B_DIM * H_DIM * G_WIN, 512, 0, stream>>>(
        qb, kb, vb, rf_k_bar, rfa_chunk, attn_dst);

    const bf16* gemm_in;
    if (big_ws) {
        gemm_in = att_ws;
    } else {
        (void)hipMemcpyAsync(kb, qbf, SZ * sizeof(bf16), hipMemcpyDeviceToDevice, stream);
        gemm_in = kb;
    }

    // 5. output projection
    if (wb16) {
        gemm_mfma<1, true><<<ggrd1, gblk, 0, stream>>>(gemm_in, wo_b, bo, 1.0f, nullptr, outf, nullptr, nullptr);
    } else {
        gemm_mfma<1, false><<<ggrd1, gblk, 0, stream>>>(gemm_in, Wo, bo, 1.0f, nullptr, outf, nullptr, nullptr);
    }
}

// Round 8
// 400.698 us; speedup vs baseline: 10.9488x; 1.0057x over previous
//
#include <hip/hip_runtime.h>
#include <hip/hip_bf16.h>

typedef __hip_bfloat16 bf16;
typedef __attribute__((ext_vector_type(8))) short bf16x8;
typedef __attribute__((ext_vector_type(4))) float f32x4;

#define E_DIM 1024
#define H_DIM 16
#define N_DIM 4096
#define B_DIM 4
#define D_DIM 64
#define G_WIN 32   // N / 128
#define NC 32      // N / 128
#define M_ROWS 16384  // N*B

#define AS1 __attribute__((address_space(1)))
#define AS3 __attribute__((address_space(3)))

__device__ __forceinline__ void cvt8(const float* __restrict__ in,
                                     bf16* __restrict__ out, int blk) {
    int i = (blk * 256 + (int)threadIdx.x) * 8;
    float4 f0 = *(const float4*)(in + i);
    float4 f1 = *(const float4*)(in + i + 4);
    union { bf16 t[8]; uint4 u; } pk;
    pk.t[0] = (bf16)f0.x; pk.t[1] = (bf16)f0.y; pk.t[2] = (bf16)f0.z; pk.t[3] = (bf16)f0.w;
    pk.t[4] = (bf16)f1.x; pk.t[5] = (bf16)f1.y; pk.t[6] = (bf16)f1.z; pk.t[7] = (bf16)f1.w;
    *(uint4*)(out + i) = pk.u;
}

// ---------------- fp32 -> bf16 bulk convert (query-only fallback) ------------
__global__ __launch_bounds__(256) void cvt_f32_bf16(
    const float* __restrict__ in, bf16* __restrict__ out)
{
    cvt8(in, out, blockIdx.x);
}

// ---------------- fused convert: query + 4 weights + stacked QKV bias --------
// blocks [0,8192): query; [8192,10240): weights (512 blocks each); 10240: bias.
__global__ __launch_bounds__(256) void cvt_all(
    const float* __restrict__ q, bf16* __restrict__ qo,
    const float* __restrict__ w0, const float* __restrict__ w1,
    const float* __restrict__ w2, const float* __restrict__ w3,
    bf16* __restrict__ o0, bf16* __restrict__ o1,
    bf16* __restrict__ o2, bf16* __restrict__ o3,
    const float* __restrict__ bq, const float* __restrict__ bk,
    const float* __restrict__ bv, float* __restrict__ biasQKV)
{
    int bid = blockIdx.x;
    if (bid < 8192) {
        cvt8(q, qo, bid);
    } else if (bid < 10240) {
        int wi = (bid - 8192) >> 9, off = (bid - 8192) & 511;
        const float* src = (wi == 0) ? w0 : (wi == 1) ? w1 : (wi == 2) ? w2 : w3;
        bf16* dst = (wi == 0) ? o0 : (wi == 1) ? o1 : (wi == 2) ? o2 : o3;
        cvt8(src, dst, off);
    } else {
        for (int i = threadIdx.x; i < 3072; i += 256)
            biasQKV[i] = (i < 1024) ? bq[i] : (i < 2048) ? bk[i - 1024] : bv[i - 2048];
    }
}

// ---------------- MFMA GEMM ----------------
// out[m,e] = sum_k A[m,k] * W[e,k]  (A bf16 row-major [M][K])
// 128x128 tile, 4 waves of 64x64, mfma_f32_16x16x32_bf16, BK=64.
// LDS layout: row r, 8 slots of 16B; slot s holds global chunk s^(r&7)
// (linear gload_lds dest + pre-swizzled source; read applies the same XOR)
// -> fragment b128 reads are 2-way bank aliased (free) instead of 8-way.
// Block mapping: chunk = bid&7 (XCD), lc = bid>>3; colt = lc>>4, rowsub = lc&15.
// MODE 0: (val + bias)*scale -> bf16 scatter [B,H,N,D]
// MODE 1: val + bias -> fp32 row-major [M][E]
// MODE 2: fused QKV; N=3072 stacked W/bias; block-uniform output select.
template<int MODE, bool WB16>
__global__ __launch_bounds__(256) void gemm_mfma(
    const bf16* __restrict__ A, const void* __restrict__ Wp,
    const float* __restrict__ bias, float scale,
    bf16* __restrict__ out_bf, float* __restrict__ out_f,
    bf16* __restrict__ out_k, bf16* __restrict__ out_v)
{
    __shared__ bf16 As[128 * 64];
    __shared__ bf16 Bs[128 * 64];
    int tid  = threadIdx.x;
    int lane = tid & 63;
    int wv   = tid >> 6;
    int wm   = (wv >> 1) * 64;
    int wn   = (wv & 1) * 64;
    int quad = lane >> 4;
    int l16  = lane & 15;
    int x7   = l16 & 7;

    int chunk  = blockIdx.x & 7;
    int lc     = blockIdx.x >> 3;
    int colt   = lc >> 4;
    int rowsub = lc & 15;
    int col0 = colt * 128;
    int row0 = (chunk * 16 + rowsub) * 128;

    f32x4 acc[4][4] = {};

    for (int k0 = 0; k0 < E_DIM; k0 += 64) {
        // A tile: 128 rows x 64 cols; slot s <- global chunk s^(r&7)
#pragma unroll
        for (int i = 0; i < 4; i++) {
            int idx = tid + i * 256;           // 0..1023
            int r = idx >> 3, s = idx & 7;
            const bf16* g = A + (size_t)(row0 + r) * E_DIM + k0 + ((s ^ (r & 7)) * 8);
            __builtin_amdgcn_global_load_lds(
                (const AS1 void*)g, (AS3 void*)(As + idx * 8), 16, 0, 0);
        }
        if constexpr (WB16) {
            const bf16* Wb = (const bf16*)Wp;
#pragma unroll
            for (int i = 0; i < 4; i++) {
                int idx = tid + i * 256;
                int r = idx >> 3, s = idx & 7;
                const bf16* g = Wb + (size_t)(col0 + r) * E_DIM + k0 + ((s ^ (r & 7)) * 8);
                __builtin_amdgcn_global_load_lds(
                    (const AS1 void*)g, (AS3 void*)(Bs + idx * 8), 16, 0, 0);
            }
        } else {
            const float* Wf = (const float*)Wp;
#pragma unroll
            for (int i = 0; i < 4; i++) {
                int idx = tid + i * 256;
                int r = idx >> 3, s = idx & 7;
                const float* wr = Wf + (size_t)(col0 + r) * E_DIM + k0 + ((s ^ (r & 7)) * 8);
                float4 f0 = *(const float4*)wr;
                float4 f1 = *(const float4*)(wr + 4);
                union { bf16 t[8]; uint4 u; } pk;
                pk.t[0] = (bf16)f0.x; pk.t[1] = (bf16)f0.y;
                pk.t[2] = (bf16)f0.z; pk.t[3] = (bf16)f0.w;
                pk.t[4] = (bf16)f1.x; pk.t[5] = (bf16)f1.y;
                pk.t[6] = (bf16)f1.z; pk.t[7] = (bf16)f1.w;
                *(uint4*)(Bs + idx * 8) = pk.u;
            }
        }
        __syncthreads();

#pragma unroll
        for (int kc = 0; kc < 2; kc++) {
            int cs = kc * 4 + quad;
            bf16x8 af[4], bfr[4];
#pragma unroll
            for (int t = 0; t < 4; t++) {
                af[t]  = *(const bf16x8*)(As + (wm + t * 16 + l16) * 64 + ((cs ^ x7) * 8));
                bfr[t] = *(const bf16x8*)(Bs + (wn + t * 16 + l16) * 64 + ((cs ^ x7) * 8));
            }
#pragma unroll
            for (int mt = 0; mt < 4; mt++)
#pragma unroll
                for (int nt = 0; nt < 4; nt++)
                    acc[mt][nt] = __builtin_amdgcn_mfma_f32_16x16x32_bf16(
                        af[mt], bfr[nt], acc[mt][nt], 0, 0, 0);
        }
        __syncthreads();
    }

    // output select (block-uniform for MODE 2)
    bf16* dst = out_bf;
    float scl = scale;
    if (MODE == 2) {
        int sel = col0 >> 10;
        dst = (sel == 0) ? out_bf : ((sel == 1) ? out_k : out_v);
        scl = (sel == 0) ? scale : 1.0f;
    }

#pragma unroll
    for (int mt = 0; mt < 4; mt++)
#pragma unroll
        for (int nt = 0; nt < 4; nt++)
#pragma unroll
            for (int rg = 0; rg < 4; rg++) {
                int m = row0 + wm + mt * 16 + quad * 4 + rg;
                int e = col0 + wn + nt * 16 + l16;
                float val = acc[mt][nt][rg];
                if (MODE == 1) {
                    out_f[(size_t)m * E_DIM + e] = val + bias[e];
                } else {
                    float v2 = (val + bias[e]) * scl;
                    int el = e & 1023;
                    int n = m >> 2, bb = m & 3;
                    int h = el >> 6, d = el & 63;
                    dst[((((size_t)bb * H_DIM + h) * N_DIM + n) * D_DIM) + d] = (bf16)v2;
                }
            }
}

// ---------------- Chunk stats (wave-parallel reductions) ----------------
__global__ __launch_bounds__(128) void chunk_stats(
    const bf16* __restrict__ q_s, const bf16* __restrict__ kbuf, const bf16* __restrict__ vbuf,
    const float* __restrict__ mqw, const float* __restrict__ mqb,
    const float* __restrict__ mqg, const float* __restrict__ mqbe,
    const float* __restrict__ mkw, const float* __restrict__ mkb,
    const float* __restrict__ mkg, const float* __restrict__ mkbe,
    float* __restrict__ rf_k_bar, float* __restrict__ rfa_chunk)
{
    int bid = blockIdx.x;
    int c = bid % NC;
    int bh = bid / NC;
    int tid = threadIdx.x;
    int lane = tid & 63;
    int wid = tid >> 6;

    __shared__ float qm[64], km[64], mu_s[64], sc[128];
    __shared__ float parts[4];

    size_t base = ((size_t)bh * N_DIM + c * 128) * D_DIM;

    if (tid < 64) {
        float s = 0.f;
        for (int p = 0; p < 128; p++) s += (float)q_s[base + p * 64 + tid];
        qm[tid] = s * (1.0f / 128.0f);
    } else {
        int d = tid - 64;
        float s = 0.f;
        for (int p = 0; p < 128; p++) s += (float)kbuf[base + p * 64 + d];
        km[d] = s * (1.0f / 128.0f);
    }
    __syncthreads();

    {
        float t;
        if (wid == 0) {
            t = mqb[lane];
            for (int d2 = 0; d2 < 64; d2++) t += qm[d2] * mqw[lane * 64 + d2];
        } else {
            t = mkb[lane];
            for (int d2 = 0; d2 < 64; d2++) t += km[d2] * mkw[lane * 64 + d2];
        }
        float s = t;
        s += __shfl_xor(s, 1);  s += __shfl_xor(s, 2);  s += __shfl_xor(s, 4);
        s += __shfl_xor(s, 8);  s += __shfl_xor(s, 16); s += __shfl_xor(s, 32);
        float mean = s * (1.0f / 64.0f);
        float x = t - mean;
        float v2 = x * x;
        v2 += __shfl_xor(v2, 1);  v2 += __shfl_xor(v2, 2);  v2 += __shfl_xor(v2, 4);
        v2 += __shfl_xor(v2, 8);  v2 += __shfl_xor(v2, 16); v2 += __shfl_xor(v2, 32);
        float rstd = rsqrtf(v2 * (1.0f / 64.0f) + 1e-5f);
        if (wid == 0) {
            qm[lane] = x * rstd * mqg[lane] + mqbe[lane];
        } else {
            float kn = x * rstd * mkg[lane] + mkbe[lane];
            km[lane] = kn;
            rf_k_bar[(size_t)bh * NC * 64 + c * 64 + lane] = kn;
        }
    }
    __syncthreads();
    if (tid < 64) mu_s[tid] = qm[tid] + km[tid];
    __syncthreads();

    float scv;
    {
        float dot = 0.f, ss = 0.f;
        const bf16* kr = kbuf + base + tid * 64;
        for (int d = 0; d < 64; d++) {
            float kv = (float)kr[d];
            dot += mu_s[d] * kv;
            ss += kv * kv;
        }
        scv = dot * 0.125f - 0.0625f * ss;
    }
    {
        float mv = scv;
        mv = fmaxf(mv, __shfl_xor(mv, 1));  mv = fmaxf(mv, __shfl_xor(mv, 2));
        mv = fmaxf(mv, __shfl_xor(mv, 4));  mv = fmaxf(mv, __shfl_xor(mv, 8));
        mv = fmaxf(mv, __shfl_xor(mv, 16)); mv = fmaxf(mv, __shfl_xor(mv, 32));
        if (lane == 0) parts[wid] = mv;
        __syncthreads();
        float mall = fmaxf(parts[0], parts[1]);
        float e = expf(scv - mall);
        float sv = e;
        sv += __shfl_xor(sv, 1);  sv += __shfl_xor(sv, 2);  sv += __shfl_xor(sv, 4);
        sv += __shfl_xor(sv, 8);  sv += __shfl_xor(sv, 16); sv += __shfl_xor(sv, 32);
        if (lane == 0) parts[2 + wid] = sv;
        __syncthreads();
        float inv = 1.0f / (parts[2] + parts[3]);
        sc[tid] = e * inv;
    }
    __syncthreads();

    if (tid < 64) {
        float acc = 0.f;
        for (int p = 0; p < 128; p++) acc += sc[p] * (float)vbuf[base + p * 64 + tid];
        rfa_chunk[(size_t)bh * NC * 64 + c * 64 + tid] = acc;
    }
}

// ---------------- Windowed attention per (b,h,g) — v5 (unchanged) ------------
__global__ __launch_bounds__(512, 4) void attn_kernel(
    const bf16* __restrict__ qin, const bf16* __restrict__ kbuf, const bf16* __restrict__ vbuf,
    const float* __restrict__ rf_k_bar, const float* __restrict__ rfa_chunk,
    bf16* __restrict__ aout)
{
    int bid = blockIdx.x;
    int g = bid & (G_WIN - 1);
    int bh = bid / G_WIN;
    int b = bh >> 4, h = bh & 15;
    int tid = threadIdx.x;
    int lane = tid & 63;
    int wv = tid >> 6;
    int q4 = lane >> 4;
    int l16 = lane & 15;

    __shared__ __align__(16) short Ks[288 * 72];
    __shared__ __align__(16) short Vt[64 * 296];

    size_t kvbase = (size_t)bh * N_DIM * D_DIM;
    int k0g = g * 128 - 128;

#pragma unroll
    for (int i = 0; i < 4; i++) {
        int ci = tid + i * 512;
        int key = ci >> 3, chc = ci & 7;
        int kidx = k0g + key; if (kidx < 0) kidx = 0;
        bf16x8 v = *(const bf16x8*)(kbuf + kvbase + (size_t)kidx * 64 + chc * 8);
        *(bf16x8*)(Ks + key * 72 + chc * 8) = v;
    }
    if (tid < 256) {
        int c = tid >> 3, chc = tid & 7;
        const float* src = rf_k_bar + (size_t)bh * NC * 64 + c * 64 + chc * 8;
        float4 f0 = *(const float4*)src;
        float4 f1 = *(const float4*)(src + 4);
        union { bf16 t[8]; bf16x8 v; } pk;
        pk.t[0] = (bf16)f0.x; pk.t[1] = (bf16)f0.y;
        pk.t[2] = (bf16)f0.z; pk.t[3] = (bf16)f0.w;
        pk.t[4] = (bf16)f1.x; pk.t[5] = (bf16)f1.y;
        pk.t[6] = (bf16)f1.z; pk.t[7] = (bf16)f1.w;
        *(bf16x8*)(Ks + (256 + c) * 72 + chc * 8) = pk.v;
    }
#pragma unroll
    for (int i = 0; i < 4; i++) {
        int ci = tid + i * 512;
        int key = ci & 255, dc = ci >> 8;
        int kidx = k0g + key; if (kidx < 0) kidx = 0;
        union { bf16x8 v; short s[8]; } u;
        u.v = *(const bf16x8*)(vbuf + kvbase + (size_t)kidx * 64 + dc * 8);
        int colp = (key & ~31) | (((key >> 2) & 3) << 3)
                 | (((key >> 4) & 1) << 2) | (key & 3);
#pragma unroll
        for (int jj = 0; jj < 8; jj++)
            Vt[(dc * 8 + jj) * 296 + colp] = u.s[jj];
    }
    if (tid < 256) {
        int d = tid >> 2, cg = tid & 3;
        const float* rc = rfa_chunk + (size_t)bh * NC * 64;
#pragma unroll
        for (int jj = 0; jj < 8; jj++) {
            int c = cg * 8 + jj;
            int p = (((c >> 2) & 3) << 3) | (((c >> 4) & 1) << 2) | (c & 3);
            union { bf16 bv; short s; } cv;
            cv.bv = (bf16)rc[(size_t)c * 64 + d];
            Vt[d * 296 + 256 + p] = cv.s;
        }
    }

    bf16x8 bq0, bq1;
    {
        const bf16* qrow = qin + kvbase + (size_t)(g * 128 + wv * 16 + l16) * 64 + q4 * 8;
        bq0 = *(const bf16x8*)qrow;
        bq1 = *(const bf16x8*)(qrow + 32);
    }

    __syncthreads();

    f32x4 acc[18] = {};
    __builtin_amdgcn_s_setprio(1);
#pragma unroll
    for (int ct = 0; ct < 18; ct++) {
        bool live = (ct < 16) ? (ct <= wv + 8 && !(g == 0 && ct < 8))
                              : ((ct == 16) ? (g > 0) : (g > 16));
        if (!live) continue;
        int r = ct * 16 + l16;
        bf16x8 ak0 = *(const bf16x8*)(Ks + r * 72 + q4 * 8);
        bf16x8 ak1 = *(const bf16x8*)(Ks + r * 72 + 32 + q4 * 8);
        acc[ct] = __builtin_amdgcn_mfma_f32_16x16x32_bf16(ak0, bq0, acc[ct], 0, 0, 0);
        acc[ct] = __builtin_amdgcn_mfma_f32_16x16x32_bf16(ak1, bq1, acc[ct], 0, 0, 0);
    }
    __builtin_amdgcn_s_setprio(0);

    int qi = wv * 16 + l16;
    float m = -1e30f;
#pragma unroll
    for (int ct = 0; ct < 18; ct++) {
        bool live = (ct < 16) ? (ct <= wv + 8 && !(g == 0 && ct < 8))
                              : ((ct == 16) ? (g > 0) : (g > 16));
        if (!live) continue;
        int jbase = ct * 16 + q4 * 4;
#pragma unroll
        for (int rg = 0; rg < 4; rg++) {
            int j = jbase + rg;
            bool ok = (j < 256) ? (k0g + j >= 0 && j <= qi + 128) : ((j - 256) < g);
            float s = ok ? acc[ct][rg] : -1e9f;
            acc[ct][rg] = s;
            m = fmaxf(m, s);
        }
    }
    m = fmaxf(m, __shfl_xor(m, 16));
    m = fmaxf(m, __shfl_xor(m, 32));

    float sum = 0.f;
#pragma unroll
    for (int ct = 0; ct < 18; ct++) {
        bool live = (ct < 16) ? (ct <= wv + 8 && !(g == 0 && ct < 8))
                              : ((ct == 16) ? (g > 0) : (g > 16));
        if (!live) continue;
#pragma unroll
        for (int rg = 0; rg < 4; rg++) {
            float p = __expf(acc[ct][rg] - m);
            acc[ct][rg] = p;
            sum += p;
        }
    }
    sum += __shfl_xor(sum, 16);
    sum += __shfl_xor(sum, 32);
    float rinv = 1.0f / sum;

    f32x4 accO[4] = {};
    __builtin_amdgcn_s_setprio(1);
#pragma unroll
    for (int cc = 0; cc < 9; cc++) {
        bool live = (cc < 8) ? (2 * cc <= wv + 8 && !(g == 0 && cc < 4)) : (g > 0);
        if (!live) continue;
        union { bf16 t[8]; bf16x8 v; } pb;
#pragma unroll
        for (int e = 0; e < 4; e++) {
            pb.t[e]     = (bf16)acc[2 * cc][e];
            pb.t[4 + e] = (bf16)acc[2 * cc + 1][e];
        }
#pragma unroll
        for (int dt = 0; dt < 4; dt++) {
            bf16x8 av = *(const bf16x8*)(Vt + (dt * 16 + l16) * 296 + (cc * 4 + q4) * 8);
            accO[dt] = __builtin_amdgcn_mfma_f32_16x16x32_bf16(av, pb.v, accO[dt], 0, 0, 0);
        }
    }
    __builtin_amdgcn_s_setprio(0);

    int nn = g * 128 + wv * 16 + l16;
    size_t obase = ((size_t)nn * B_DIM + b) * E_DIM + h * 64;
#pragma unroll
    for (int dt = 0; dt < 4; dt++) {
        union { bf16 t[4]; uint2 u; } o;
#pragma unroll
        for (int rg = 0; rg < 4; rg++) o.t[rg] = (bf16)(accO[dt][rg] * rinv);
        *(uint2*)(aout + obase + dt * 16 + q4 * 4) = o.u;
    }
}

extern "C" void kernel_launch(void* const* d_in, const int* in_sizes, int n_in,
                              void* d_out, int out_size, void* d_ws, size_t ws_size,
                              hipStream_t stream) {
    const float* query = (const float*)d_in[0];
    const float* Wq   = (const float*)d_in[1];
    const float* bq   = (const float*)d_in[2];
    const float* Wk   = (const float*)d_in[3];
    const float* bk   = (const float*)d_in[4];
    const float* Wv   = (const float*)d_in[5];
    const float* bv   = (const float*)d_in[6];
    const float* Wo   = (const float*)d_in[7];
    const float* bo   = (const float*)d_in[8];
    const float* mqw  = (const float*)d_in[9];
    const float* mqb  = (const float*)d_in[10];
    const float* mqg  = (const float*)d_in[11];
    const float* mqbe = (const float*)d_in[12];
    const float* mkw  = (const float*)d_in[13];
    const float* mkb  = (const float*)d_in[14];
    const float* mkg  = (const float*)d_in[15];
    const float* mkbe = (const float*)d_in[16];

    const size_t SZ = (size_t)B_DIM * H_DIM * N_DIM * D_DIM; // 16,777,216 elems
    const size_t STATS = (size_t)B_DIM * H_DIM * NC * D_DIM; // 131,072 elems

    bf16* kb = (bf16*)d_ws;
    bf16* vb = kb + SZ;
    float* rf_k_bar  = (float*)(vb + SZ);
    float* rfa_chunk = rf_k_bar + STATS;

    size_t base_bytes = 2 * SZ * sizeof(bf16) + 2 * STATS * sizeof(float);
    size_t wmat = (size_t)E_DIM * E_DIM;
    size_t wb16_bytes = base_bytes + 4 * wmat * sizeof(bf16) + 3072 * sizeof(float);
    bool wb16   = ws_size >= wb16_bytes;
    bool big_ws = ws_size >= wb16_bytes + SZ * sizeof(bf16);
    bf16* wq_b = (bf16*)((char*)d_ws + base_bytes);
    bf16* wk_b = wq_b + wmat;
    bf16* wv_b = wk_b + wmat;
    bf16* wo_b = wv_b + wmat;
    float* biasQKV = (float*)(wo_b + wmat);          // 3072 floats
    bf16* att_ws = (bf16*)(biasQKV + 3072);

    float* outf = (float*)d_out;
    bf16* qb  = (bf16*)d_out;      // 32 MiB
    bf16* qbf = qb + SZ;           // 32 MiB

    dim3 gblk(256);
    int ggrd1 = (E_DIM / 128) * (M_ROWS / 128);      // 1024 blocks
    int ggrd3 = 3 * ggrd1;                           // 3072 blocks

    // 1. converts (one kernel when workspace allows)
    if (wb16) {
        cvt_all<<<10241, 256, 0, stream>>>(
            query, qbf, Wq, Wk, Wv, Wo, wq_b, wk_b, wv_b, wo_b,
            bq, bk, bv, biasQKV);
    } else {
        cvt_f32_bf16<<<(M_ROWS * E_DIM) / (256 * 8), 256, 0, stream>>>(query, qbf);
    }

    // 2. projections
    if (wb16) {
        gemm_mfma<2, true><<<ggrd3, gblk, 0, stream>>>(
            qbf, wq_b, biasQKV, 0.125f, qb, nullptr, kb, vb);
    } else {
        gemm_mfma<0, false><<<ggrd1, gblk, 0, stream>>>(qbf, Wq, bq, 0.125f, qb, nullptr, nullptr, nullptr);
        gemm_mfma<0, false><<<ggrd1, gblk, 0, stream>>>(qbf, Wk, bk, 1.0f, kb, nullptr, nullptr, nullptr);
        gemm_mfma<0, false><<<ggrd1, gblk, 0, stream>>>(qbf, Wv, bv, 1.0f, vb, nullptr, nullptr, nullptr);
    }

    // 3. chunk stats
    chunk_stats<<<B_DIM * H_DIM * NC, 128, 0, stream>>>(
        qb, kb, vb, mqw, mqb, mqg, mqbe, mkw, mkb, mkg, mkbe, rf_k_bar, rfa_chunk);

    // 4. attention
    bf16* attn_dst = big_ws ? att_ws : qbf;
    attn_kernel<<<B_DIM * H_DIM * G_WIN, 512, 0, stream>>>(
        qb, kb, vb, rf_k_bar, rfa_chunk, attn_dst);

    const bf16* gemm_in;
    if (big_ws) {
        gemm_in = att_ws;
    } else {
        (void)hipMemcpyAsync(kb, qbf, SZ * sizeof(bf16), hipMemcpyDeviceToDevice, stream);
        gemm_in = kb;
    }

    // 5. output projection
    if (wb16) {
        gemm_mfma<1, true><<<ggrd1, gblk, 0, stream>>>(gemm_in, wo_b, bo, 1.0f, nullptr, outf, nullptr, nullptr);
    } else {
        gemm_mfma<1, false><<<ggrd1, gblk, 0, stream>>>(gemm_in, Wo, bo, 1.0f, nullptr, outf, nullptr, nullptr);
    }
}